// Round 2
// baseline (782.861 us; speedup 1.0000x reference)
//
#include <hip/hip_runtime.h>

// ---------- types ----------
typedef __bf16 bf16x8 __attribute__((ext_vector_type(8)));
typedef unsigned short u16x8 __attribute__((ext_vector_type(8)));
typedef float f32x4 __attribute__((ext_vector_type(4)));

__device__ __forceinline__ unsigned short f2bf(float f) {
  unsigned u = __builtin_bit_cast(unsigned, f);
  u += 0x7FFFu + ((u >> 16) & 1u);   // round-to-nearest-even
  return (unsigned short)(u >> 16);
}

__device__ __forceinline__ f32x4 mfma16(u16x8 a, u16x8 b, f32x4 c) {
  return __builtin_amdgcn_mfma_f32_16x16x32_bf16(
      __builtin_bit_cast(bf16x8, a), __builtin_bit_cast(bf16x8, b), c, 0, 0, 0);
}

// ---------- f32 -> bf16 convert ----------
__global__ __launch_bounds__(256) void k_conv(const float* __restrict__ src,
                                              unsigned short* __restrict__ dst, int n4) {
  int i = blockIdx.x * 256 + threadIdx.x;
  int stride = gridDim.x * 256;
  for (; i < n4; i += stride) {
    float4 v = ((const float4*)src)[i];
    ushort4 o;
    o.x = f2bf(v.x); o.y = f2bf(v.y); o.z = f2bf(v.z); o.w = f2bf(v.w);
    ((ushort4*)dst)[i] = o;
  }
}

// ---------- GEMM: C[M,N] f32 = A[M,K]bf16 * B[N,K]^T bf16 + bias ----------
// 128x128 tile, BK=32, 4 waves (2x2), each wave 64x64 (4x4 frags of 16x16x32)
__global__ __launch_bounds__(256) void k_gemm(const unsigned short* __restrict__ A,
                                              const unsigned short* __restrict__ B,
                                              float* __restrict__ C, int M, int N, int K,
                                              const float* __restrict__ bias0,
                                              const float* __restrict__ bias1) {
  __shared__ unsigned short lA[128 * 40];  // stride 40 shorts: 16B-aligned rows, ~2-way banks
  __shared__ unsigned short lB[128 * 40];
  const int tid = threadIdx.x;
  const int l = tid & 63, w = tid >> 6;
  const int wm = w >> 1, wn = w & 1;
  const int lr = l & 15, lg = l >> 4;
  const int m0 = blockIdx.y * 128, n0 = blockIdx.x * 128;

  const f32x4 zero4 = {0.f, 0.f, 0.f, 0.f};
  f32x4 acc[4][4];
#pragma unroll
  for (int i = 0; i < 4; i++)
#pragma unroll
    for (int j = 0; j < 4; j++) acc[i][j] = zero4;

  for (int k0 = 0; k0 < K; k0 += 32) {
    __syncthreads();
#pragma unroll
    for (int rr = 0; rr < 2; rr++) {
      int c = tid + rr * 256;          // 0..511 chunks of 8 elems
      int row = c >> 2, c8 = (c & 3) * 8;
      int ra = m0 + row; ra = ra < M ? ra : M - 1;   // clamp partial-M tiles
      u16x8 va = *(const u16x8*)(A + (long)ra * K + k0 + c8);
      *(u16x8*)(&lA[row * 40 + c8]) = va;
      u16x8 vb = *(const u16x8*)(B + (long)(n0 + row) * K + k0 + c8);
      *(u16x8*)(&lB[row * 40 + c8]) = vb;
    }
    __syncthreads();
    u16x8 af[4], bfr[4];
#pragma unroll
    for (int mb = 0; mb < 4; mb++)
      af[mb] = *(const u16x8*)(&lA[(wm * 64 + mb * 16 + lr) * 40 + lg * 8]);
#pragma unroll
    for (int nb = 0; nb < 4; nb++)
      bfr[nb] = *(const u16x8*)(&lB[(wn * 64 + nb * 16 + lr) * 40 + lg * 8]);
#pragma unroll
    for (int mb = 0; mb < 4; mb++)
#pragma unroll
      for (int nb = 0; nb < 4; nb++) acc[mb][nb] = mfma16(af[mb], bfr[nb], acc[mb][nb]);
  }

#pragma unroll
  for (int mb = 0; mb < 4; mb++)
#pragma unroll
    for (int nb = 0; nb < 4; nb++)
#pragma unroll
      for (int r = 0; r < 4; r++) {
        int row = m0 + wm * 64 + mb * 16 + lg * 4 + r;   // C/D: col=lane&15, row=(lane>>4)*4+r
        if (row < M) {
          int col = n0 + wn * 64 + nb * 16 + lr;
          float b = 0.f;
          if (col < 1536) { if (bias0) b = bias0[col]; }
          else            { if (bias1) b = bias1[col - 1536]; }
          C[(long)row * N + col] = acc[mb][nb][r] + b;
        }
      }
}

// ---------- per-row postproc over 1536 cols: optional RMSNorm, always f32->bf16 ----------
template <bool NORM>
__global__ __launch_bounds__(256) void k_postproc(const float* __restrict__ src, int ld, int off,
                                                  const float* __restrict__ w,
                                                  unsigned short* __restrict__ dst) {
  const int row = blockIdx.x;
  const float* s = src + (long)row * ld + off;
  float v[6];
  float ss = 0.f;
#pragma unroll
  for (int i = 0; i < 6; i++) {
    v[i] = s[threadIdx.x + i * 256];
    ss += v[i] * v[i];
  }
  float scale = 1.f;
  if (NORM) {
#pragma unroll
    for (int o = 1; o < 64; o <<= 1) ss += __shfl_xor(ss, o, 64);
    __shared__ float red[4];
    if ((threadIdx.x & 63) == 0) red[threadIdx.x >> 6] = ss;
    __syncthreads();
    float tot = red[0] + red[1] + red[2] + red[3];
    scale = rsqrtf(tot * (1.f / 1536.f) + 1e-6f);
  }
  unsigned short* d = dst + (long)row * 1536;
#pragma unroll
  for (int i = 0; i < 6; i++) {
    float x = v[i] * scale;
    if (NORM) x *= w[threadIdx.x + i * 256];
    d[threadIdx.x + i * 256] = f2bf(x);
  }
}

// ---------- fused 3-way flash attention ----------
// grid (168 q-tiles of 64, 12 heads), 256 threads = 4 waves, each wave 16 q rows.
// phase 0: img (257 keys), phase 1: txt (512 keys, masked by context_lens),
// phase 2: audio (frame = qtile/8, <=32 keys, masked by audio_context_lens[frame]).
__global__ __launch_bounds__(256) void k_attn(
    const unsigned short* __restrict__ qb, const unsigned short* __restrict__ kt,
    const unsigned short* __restrict__ vt, const unsigned short* __restrict__ ki,
    const unsigned short* __restrict__ vi, const unsigned short* __restrict__ ka,
    const unsigned short* __restrict__ va, const int* __restrict__ clen_p,
    const int* __restrict__ alens, float* __restrict__ out) {
  __shared__ unsigned short lK[32 * 136];   // [key][d], stride 136 (16B-aligned, ~2-way banks)
  __shared__ unsigned short lV[32 * 130];   // [key][d], stride 130 (conflict-free u16 reads)
  __shared__ unsigned short lP[4][16 * 40]; // per-wave P transpose buffer

  const int qt = blockIdx.x, h = blockIdx.y;
  const int tid = threadIdx.x, l = tid & 63, w = tid >> 6;
  const int lr = l & 15, lg = l >> 4;
  const int q0 = qt * 64;
  const int frame = qt >> 3;
  const float scale = 0.08838834764831845f;  // 1/sqrt(128)

  u16x8 qf[4];
  {
    const unsigned short* qp = qb + (long)(q0 + w * 16 + lr) * 1536 + h * 128;
#pragma unroll
    for (int kk = 0; kk < 4; kk++) qf[kk] = *(const u16x8*)(qp + kk * 32 + lg * 8);
  }

  const f32x4 zero4 = {0.f, 0.f, 0.f, 0.f};
  f32x4 osum[8];
#pragma unroll
  for (int nb = 0; nb < 8; nb++) osum[nb] = zero4;

  for (int ph = 0; ph < 3; ph++) {
    const unsigned short *kp, *vp;
    int nk, klen;
    if (ph == 0)      { kp = ki; vp = vi; nk = 257; klen = 257; }
    else if (ph == 1) { kp = kt; vp = vt; nk = 512; klen = clen_p[0]; }
    else { kp = ka + (long)frame * 32 * 1536; vp = va + (long)frame * 32 * 1536;
           nk = 32; klen = alens[frame]; }

    float m[4], lse[4];
#pragma unroll
    for (int r = 0; r < 4; r++) { m[r] = -1e30f; lse[r] = 0.f; }
    f32x4 oacc[8];
#pragma unroll
    for (int nb = 0; nb < 8; nb++) oacc[nb] = zero4;

    const int ntiles = (klen + 31) >> 5;
    for (int t = 0; t < ntiles; t++) {
      const int kb0 = t * 32;
      __syncthreads();   // prev-iter readers done before restage
#pragma unroll
      for (int rr = 0; rr < 2; rr++) {
        int c = tid + rr * 256;          // 0..511: key=c>>4, 16B d-chunk=(c&15)
        int key = c >> 4, d8 = (c & 15) * 8;
        u16x8 kv = {0, 0, 0, 0, 0, 0, 0, 0};
        u16x8 vv = {0, 0, 0, 0, 0, 0, 0, 0};
        if (kb0 + key < nk) {
          kv = *(const u16x8*)(kp + (long)(kb0 + key) * 1536 + h * 128 + d8);
          vv = *(const u16x8*)(vp + (long)(kb0 + key) * 1536 + h * 128 + d8);
        }
        *(u16x8*)(&lK[key * 136 + d8]) = kv;
#pragma unroll
        for (int j = 0; j < 8; j++) lV[key * 130 + d8 + j] = vv[j];
      }
      __syncthreads();

      // S = Q(16x128) * K^T(128x32) as 2 key-blocks of 16
      f32x4 s0 = zero4, s1 = zero4;
#pragma unroll
      for (int kk = 0; kk < 4; kk++) {
        u16x8 k0f = *(const u16x8*)(&lK[(lr) * 136 + kk * 32 + lg * 8]);
        u16x8 k1f = *(const u16x8*)(&lK[(16 + lr) * 136 + kk * 32 + lg * 8]);
        s0 = mfma16(qf[kk], k0f, s0);
        s1 = mfma16(qf[kk], k1f, s1);
      }

      const bool v0 = (kb0 + lr) < klen;
      const bool v1 = (kb0 + 16 + lr) < klen;
      float p0[4], p1[4], pm[4];
#pragma unroll
      for (int r = 0; r < 4; r++) {
        float a = v0 ? s0[r] * scale : -1e30f;
        float b = v1 ? s1[r] * scale : -1e30f;
        p0[r] = a; p1[r] = b;
        pm[r] = fmaxf(a, b);
      }
#pragma unroll
      for (int o = 1; o < 16; o <<= 1) {
#pragma unroll
        for (int r = 0; r < 4; r++) pm[r] = fmaxf(pm[r], __shfl_xor(pm[r], o, 64));
      }
      float alpha[4], rs[4];
#pragma unroll
      for (int r = 0; r < 4; r++) {
        float mn = fmaxf(m[r], pm[r]);
        alpha[r] = __expf(m[r] - mn);
        m[r] = mn;
        p0[r] = __expf(p0[r] - mn);
        p1[r] = __expf(p1[r] - mn);
        rs[r] = p0[r] + p1[r];
      }
#pragma unroll
      for (int o = 1; o < 16; o <<= 1) {
#pragma unroll
        for (int r = 0; r < 4; r++) rs[r] += __shfl_xor(rs[r], o, 64);
      }
#pragma unroll
      for (int r = 0; r < 4; r++) lse[r] = lse[r] * alpha[r] + rs[r];
#pragma unroll
      for (int nb = 0; nb < 8; nb++)
#pragma unroll
        for (int r = 0; r < 4; r++) oacc[nb][r] *= alpha[r];

      // P (C-layout) -> LDS -> A-layout frag
#pragma unroll
      for (int r = 0; r < 4; r++) {
        lP[w][(lg * 4 + r) * 40 + lr] = f2bf(p0[r]);
        lP[w][(lg * 4 + r) * 40 + 16 + lr] = f2bf(p1[r]);
      }
      __syncthreads();

      u16x8 pa = *(const u16x8*)(&lP[w][lr * 40 + lg * 8]);
#pragma unroll
      for (int nb = 0; nb < 8; nb++) {
        u16x8 vf;
#pragma unroll
        for (int j = 0; j < 8; j++) vf[j] = lV[(lg * 8 + j) * 130 + nb * 16 + lr];
        oacc[nb] = mfma16(pa, vf, oacc[nb]);
      }
    }

    float inv[4];
#pragma unroll
    for (int r = 0; r < 4; r++) inv[r] = 1.f / lse[r];
#pragma unroll
    for (int nb = 0; nb < 8; nb++)
#pragma unroll
      for (int r = 0; r < 4; r++) osum[nb][r] += oacc[nb][r] * inv[r];
  }

#pragma unroll
  for (int nb = 0; nb < 8; nb++)
#pragma unroll
    for (int r = 0; r < 4; r++)
      out[(long)(q0 + w * 16 + lg * 4 + r) * 1536 + h * 128 + nb * 16 + lr] = osum[nb][r];
}

// ---------- launcher ----------
extern "C" void kernel_launch(void* const* d_in, const int* in_sizes, int n_in,
                              void* d_out, int out_size, void* d_ws, size_t ws_size,
                              hipStream_t stream) {
  (void)in_sizes; (void)n_in; (void)out_size; (void)ws_size;
  const float* x    = (const float*)d_in[0];
  const float* ctx  = (const float*)d_in[1];
  const float* aud  = (const float*)d_in[2];
  const float* Wq   = (const float*)d_in[3];
  const float* bq   = (const float*)d_in[4];
  const float* Wk   = (const float*)d_in[5];
  const float* bk   = (const float*)d_in[6];
  const float* Wv   = (const float*)d_in[7];
  const float* bv   = (const float*)d_in[8];
  const float* Wki  = (const float*)d_in[9];
  const float* bki  = (const float*)d_in[10];
  const float* Wvi  = (const float*)d_in[11];
  const float* bvi  = (const float*)d_in[12];
  const float* Wo   = (const float*)d_in[13];
  const float* bo   = (const float*)d_in[14];
  const float* nqw  = (const float*)d_in[15];
  const float* nkw  = (const float*)d_in[16];
  const float* nkiw = (const float*)d_in[17];
  const float* Wkp  = (const float*)d_in[18];
  const float* Wvp  = (const float*)d_in[19];
  const int* clen   = (const int*)d_in[20];
  const int* alens  = (const int*)d_in[21];
  float* out = (float*)d_out;

  char* ws = (char*)d_ws;
  size_t o = 0;
  auto alloc = [&](size_t bytes) { char* p = ws + o; o += bytes; return p; };
  unsigned short* x_bf    = (unsigned short*)alloc(33030144);  // 10752x1536
  unsigned short* ctx_bf  = (unsigned short*)alloc(2362368);   // 769x1536
  unsigned short* aud_bf  = (unsigned short*)alloc(1032192);   // 672x768
  unsigned short* Wq_bf   = (unsigned short*)alloc(4718592);
  unsigned short* Wo_bf   = (unsigned short*)alloc(4718592);
  unsigned short* Wkv_bf  = (unsigned short*)alloc(9437184);   // [Wk;Wv] 3072x1536
  unsigned short* Wkvi_bf = (unsigned short*)alloc(9437184);   // [Wki;Wvi]
  unsigned short* Wkva_bf = (unsigned short*)alloc(4718592);   // [Wkp;Wvp] 3072x768
  float* q_f32   = (float*)alloc(66060288);                    // also reused as attn_f32
  float* kvt_f32 = (float*)alloc(6291456);                     // 512x3072
  float* kvi_f32 = (float*)alloc(3158016);                     // 257x3072
  float* kva_f32 = (float*)alloc(8257536);                     // 672x3072
  unsigned short* q_bf  = (unsigned short*)alloc(33030144);
  unsigned short* kt_bf = (unsigned short*)alloc(1572864);
  unsigned short* vt_bf = (unsigned short*)alloc(1572864);
  unsigned short* ki_bf = (unsigned short*)alloc(789504);
  unsigned short* vi_bf = (unsigned short*)alloc(789504);
  unsigned short* ka_bf = (unsigned short*)alloc(2064384);
  unsigned short* va_bf = (unsigned short*)alloc(2064384);
  float* attn_f32 = q_f32;          // q_f32 dead after its rmsnorm
  unsigned short* attn_bf = x_bf;   // x_bf dead after Q GEMM

  auto conv = [&](const float* src, unsigned short* dst, int n) {
    int n4 = n >> 2;
    int grid = (n4 + 255) / 256; if (grid > 1024) grid = 1024;
    k_conv<<<grid, 256, 0, stream>>>(src, dst, n4);
  };

  conv(x, x_bf, 10752 * 1536);
  conv(ctx, ctx_bf, 769 * 1536);
  conv(aud, aud_bf, 672 * 768);
  conv(Wq, Wq_bf, 1536 * 1536);
  conv(Wo, Wo_bf, 1536 * 1536);
  conv(Wk, Wkv_bf, 1536 * 1536);
  conv(Wv, Wkv_bf + 1536 * 1536, 1536 * 1536);
  conv(Wki, Wkvi_bf, 1536 * 1536);
  conv(Wvi, Wkvi_bf + 1536 * 1536, 1536 * 1536);
  conv(Wkp, Wkva_bf, 1536 * 768);
  conv(Wvp, Wkva_bf + 1536 * 768, 1536 * 768);

  // projections
  k_gemm<<<dim3(12, 84), 256, 0, stream>>>(x_bf, Wq_bf, q_f32, 10752, 1536, 1536, bq, nullptr);
  k_gemm<<<dim3(24, 4), 256, 0, stream>>>(ctx_bf + 257 * 1536, Wkv_bf, kvt_f32, 512, 3072, 1536, bk, bv);
  k_gemm<<<dim3(24, 3), 256, 0, stream>>>(ctx_bf, Wkvi_bf, kvi_f32, 257, 3072, 1536, bki, bvi);
  k_gemm<<<dim3(24, 6), 256, 0, stream>>>(aud_bf, Wkva_bf, kva_f32, 672, 3072, 768, nullptr, nullptr);

  // norms / bf16 conversion
  k_postproc<true><<<10752, 256, 0, stream>>>(q_f32, 1536, 0, nqw, q_bf);
  k_postproc<true><<<512, 256, 0, stream>>>(kvt_f32, 3072, 0, nkw, kt_bf);
  k_postproc<false><<<512, 256, 0, stream>>>(kvt_f32, 3072, 1536, nullptr, vt_bf);
  k_postproc<true><<<257, 256, 0, stream>>>(kvi_f32, 3072, 0, nkiw, ki_bf);
  k_postproc<false><<<257, 256, 0, stream>>>(kvi_f32, 3072, 1536, nullptr, vi_bf);
  k_postproc<false><<<672, 256, 0, stream>>>(kva_f32, 3072, 0, nullptr, ka_bf);
  k_postproc<false><<<672, 256, 0, stream>>>(kva_f32, 3072, 1536, nullptr, va_bf);

  // fused img+txt+audio attention, writes summed context (f32)
  k_attn<<<dim3(168, 12), 256, 0, stream>>>(q_bf, kt_bf, vt_bf, ki_bf, vi_bf, ka_bf, va_bf,
                                            clen, alens, attn_f32);

  conv(attn_f32, attn_bf, 10752 * 1536);

  // output projection
  k_gemm<<<dim3(12, 84), 256, 0, stream>>>(attn_bf, Wo_bf, out, 10752, 1536, 1536, bo, nullptr);
}

// Round 3
// 776.948 us; speedup vs baseline: 1.0076x; 1.0076x over previous
//
#include <hip/hip_runtime.h>

// ---------- types ----------
typedef __bf16 bf16x8 __attribute__((ext_vector_type(8)));
typedef unsigned short u16x8 __attribute__((ext_vector_type(8)));
typedef float f32x4 __attribute__((ext_vector_type(4)));

__device__ __forceinline__ unsigned short f2bf(float f) {
  unsigned u = __builtin_bit_cast(unsigned, f);
  u += 0x7FFFu + ((u >> 16) & 1u);   // round-to-nearest-even
  return (unsigned short)(u >> 16);
}

__device__ __forceinline__ f32x4 mfma16(u16x8 a, u16x8 b, f32x4 c) {
  return __builtin_amdgcn_mfma_f32_16x16x32_bf16(
      __builtin_bit_cast(bf16x8, a), __builtin_bit_cast(bf16x8, b), c, 0, 0, 0);
}

// async global->LDS, 16B per lane; LDS dest must be wave-uniform base (+lane*16)
#define GLD16(gp, lp)                                                              \
  __builtin_amdgcn_global_load_lds((const __attribute__((address_space(1))) void*)(gp), \
                                   (__attribute__((address_space(3))) void*)(lp), 16, 0, 0)

// ---------- f32 -> bf16 convert ----------
__global__ __launch_bounds__(256) void k_conv(const float* __restrict__ src,
                                              unsigned short* __restrict__ dst, int n4) {
  int i = blockIdx.x * 256 + threadIdx.x;
  int stride = gridDim.x * 256;
  for (; i < n4; i += stride) {
    float4 v = ((const float4*)src)[i];
    ushort4 o;
    o.x = f2bf(v.x); o.y = f2bf(v.y); o.z = f2bf(v.z); o.w = f2bf(v.w);
    ((ushort4*)dst)[i] = o;
  }
}

// ---------- GEMM: C[M,N] f32 = A[M,K]bf16 * B[N,K]^T bf16 + bias ----------
// 128x128 tile, BK=32, 4 waves (2x2), each wave 64x64 (4x4 frags of 16x16x32).
// m97 structure: global_load_lds width-16 staging into linear LDS, 2 barriers/K-step.
__global__ __launch_bounds__(256) void k_gemm(const unsigned short* __restrict__ A,
                                              const unsigned short* __restrict__ B,
                                              float* __restrict__ C, int M, int N, int K,
                                              const float* __restrict__ bias0,
                                              const float* __restrict__ bias1) {
  __shared__ unsigned short lA[128 * 32];  // linear: row-major [128][32], 64B rows
  __shared__ unsigned short lB[128 * 32];
  const int tid = threadIdx.x;
  const int l = tid & 63, w = tid >> 6;
  const int wm = w >> 1, wn = w & 1;
  const int lr = l & 15, lg = l >> 4;
  const int m0 = blockIdx.y * 128, n0 = blockIdx.x * 128;

  // staging geometry: wave w, issue i in {0,1}: rows [i*64 + w*16, +16); lane l ->
  // row += l>>2, 16B k-chunk = (l&3)*8 shorts. LDS dest = wave-uniform row base.
  const int srow = w * 16 + (l >> 2);
  const int sk8 = (l & 3) * 8;
  int raA0 = m0 + srow;       if (raA0 >= M) raA0 = M - 1;
  int raA1 = m0 + 64 + srow;  if (raA1 >= M) raA1 = M - 1;
  const long rbB0 = (long)(n0 + srow) * K;        // N tiles always full (N % 128 == 0)
  const long rbB1 = (long)(n0 + 64 + srow) * K;
  const long raA0o = (long)raA0 * K, raA1o = (long)raA1 * K;
  unsigned short* ldsA0 = &lA[(w * 16) * 32];
  unsigned short* ldsA1 = &lA[(64 + w * 16) * 32];
  unsigned short* ldsB0 = &lB[(w * 16) * 32];
  unsigned short* ldsB1 = &lB[(64 + w * 16) * 32];

  const f32x4 zero4 = {0.f, 0.f, 0.f, 0.f};
  f32x4 acc[4][4];
#pragma unroll
  for (int i = 0; i < 4; i++)
#pragma unroll
    for (int j = 0; j < 4; j++) acc[i][j] = zero4;

  for (int k0 = 0; k0 < K; k0 += 32) {
    __syncthreads();                       // prev-iter frag readers done
    GLD16(A + raA0o + k0 + sk8, ldsA0);
    GLD16(A + raA1o + k0 + sk8, ldsA1);
    GLD16(B + rbB0 + k0 + sk8, ldsB0);
    GLD16(B + rbB1 + k0 + sk8, ldsB1);
    __syncthreads();                       // drains vmcnt before barrier (compiler)

    u16x8 af[4], bfr[4];
#pragma unroll
    for (int mb = 0; mb < 4; mb++)
      af[mb] = *(const u16x8*)(&lA[(wm * 64 + mb * 16 + lr) * 32 + lg * 8]);
#pragma unroll
    for (int nb = 0; nb < 4; nb++)
      bfr[nb] = *(const u16x8*)(&lB[(wn * 64 + nb * 16 + lr) * 32 + lg * 8]);
#pragma unroll
    for (int mb = 0; mb < 4; mb++)
#pragma unroll
      for (int nb = 0; nb < 4; nb++) acc[mb][nb] = mfma16(af[mb], bfr[nb], acc[mb][nb]);
  }

#pragma unroll
  for (int mb = 0; mb < 4; mb++)
#pragma unroll
    for (int nb = 0; nb < 4; nb++)
#pragma unroll
      for (int r = 0; r < 4; r++) {
        int row = m0 + wm * 64 + mb * 16 + lg * 4 + r;   // C/D: col=lane&15, row=(lane>>4)*4+r
        if (row < M) {
          int col = n0 + wn * 64 + nb * 16 + lr;
          float b = 0.f;
          if (col < 1536) { if (bias0) b = bias0[col]; }
          else            { if (bias1) b = bias1[col - 1536]; }
          C[(long)row * N + col] = acc[mb][nb][r] + b;
        }
      }
}

// ---------- per-row postproc over 1536 cols: optional RMSNorm, always f32->bf16 ----------
template <bool NORM>
__global__ __launch_bounds__(256) void k_postproc(const float* __restrict__ src, int ld, int off,
                                                  const float* __restrict__ w,
                                                  unsigned short* __restrict__ dst) {
  const int row = blockIdx.x;
  const float* s = src + (long)row * ld + off;
  float v[6];
  float ss = 0.f;
#pragma unroll
  for (int i = 0; i < 6; i++) {
    v[i] = s[threadIdx.x + i * 256];
    ss += v[i] * v[i];
  }
  float scale = 1.f;
  if (NORM) {
#pragma unroll
    for (int o = 1; o < 64; o <<= 1) ss += __shfl_xor(ss, o, 64);
    __shared__ float red[4];
    if ((threadIdx.x & 63) == 0) red[threadIdx.x >> 6] = ss;
    __syncthreads();
    float tot = red[0] + red[1] + red[2] + red[3];
    scale = rsqrtf(tot * (1.f / 1536.f) + 1e-6f);
  }
  unsigned short* d = dst + (long)row * 1536;
#pragma unroll
  for (int i = 0; i < 6; i++) {
    float x = v[i] * scale;
    if (NORM) x *= w[threadIdx.x + i * 256];
    d[threadIdx.x + i * 256] = f2bf(x);
  }
}

// ---------- fused 3-way flash attention ----------
// grid (168 q-tiles of 64, 12 heads), 256 threads = 4 waves, each wave 16 q rows.
// V stored TRANSPOSED in LDS -> PV B-fragments are single ds_read_b128.
// Output written directly as bf16.
__global__ __launch_bounds__(256) void k_attn(
    const unsigned short* __restrict__ qb, const unsigned short* __restrict__ kt,
    const unsigned short* __restrict__ vt, const unsigned short* __restrict__ ki,
    const unsigned short* __restrict__ vi, const unsigned short* __restrict__ ka,
    const unsigned short* __restrict__ va, const int* __restrict__ clen_p,
    const int* __restrict__ alens, unsigned short* __restrict__ out) {
  __shared__ unsigned short lK[32 * 136];   // [key][d], stride 136 (2-way banks, disjoint b128)
  __shared__ unsigned short lVt[128 * 40];  // [d][key], stride 40 (b128 reads conflict-free)
  __shared__ unsigned short lP[4][16 * 40]; // per-wave P transpose buffer

  const int qt = blockIdx.x, h = blockIdx.y;
  const int tid = threadIdx.x, l = tid & 63, w = tid >> 6;
  const int lr = l & 15, lg = l >> 4;
  const int q0 = qt * 64;
  const int frame = qt >> 3;
  const float scale = 0.08838834764831845f;  // 1/sqrt(128)

  u16x8 qf[4];
  {
    const unsigned short* qp = qb + (long)(q0 + w * 16 + lr) * 1536 + h * 128;
#pragma unroll
    for (int kk = 0; kk < 4; kk++) qf[kk] = *(const u16x8*)(qp + kk * 32 + lg * 8);
  }

  const f32x4 zero4 = {0.f, 0.f, 0.f, 0.f};
  f32x4 osum[8];
#pragma unroll
  for (int nb = 0; nb < 8; nb++) osum[nb] = zero4;

  for (int ph = 0; ph < 3; ph++) {
    const unsigned short *kp, *vp;
    int nk, klen;
    if (ph == 0)      { kp = ki; vp = vi; nk = 257; klen = 257; }
    else if (ph == 1) { kp = kt; vp = vt; nk = 512; klen = clen_p[0]; }
    else { kp = ka + (long)frame * 32 * 1536; vp = va + (long)frame * 32 * 1536;
           nk = 32; klen = alens[frame]; }

    float m[4], lse[4];
#pragma unroll
    for (int r = 0; r < 4; r++) { m[r] = -1e30f; lse[r] = 0.f; }
    f32x4 oacc[8];
#pragma unroll
    for (int nb = 0; nb < 8; nb++) oacc[nb] = zero4;

    const int ntiles = (klen + 31) >> 5;
    for (int t = 0; t < ntiles; t++) {
      const int kb0 = t * 32;
      __syncthreads();   // prev-iter readers done before restage
#pragma unroll
      for (int rr = 0; rr < 2; rr++) {
        int c = tid + rr * 256;
        // K staging: key = c>>4 (coalesced rows), one b128 LDS write
        {
          int key = c >> 4, d8 = (c & 15) * 8;
          u16x8 kv = {0, 0, 0, 0, 0, 0, 0, 0};
          if (kb0 + key < nk)
            kv = *(const u16x8*)(kp + (long)(kb0 + key) * 1536 + h * 128 + d8);
          *(u16x8*)(&lK[key * 136 + d8]) = kv;
        }
        // V staging transposed: key = c&31 -> row-uniform scalar writes per half-wave
        {
          int key = c & 31, d8 = (c >> 5) * 8;
          u16x8 vv = {0, 0, 0, 0, 0, 0, 0, 0};
          if (kb0 + key < nk)
            vv = *(const u16x8*)(vp + (long)(kb0 + key) * 1536 + h * 128 + d8);
#pragma unroll
          for (int j = 0; j < 8; j++) lVt[(d8 + j) * 40 + key] = vv[j];
        }
      }
      __syncthreads();

      // S = Q(16x128) * K^T(128x32) as 2 key-blocks of 16
      f32x4 s0 = zero4, s1 = zero4;
#pragma unroll
      for (int kk = 0; kk < 4; kk++) {
        u16x8 k0f = *(const u16x8*)(&lK[(lr) * 136 + kk * 32 + lg * 8]);
        u16x8 k1f = *(const u16x8*)(&lK[(16 + lr) * 136 + kk * 32 + lg * 8]);
        s0 = mfma16(qf[kk], k0f, s0);
        s1 = mfma16(qf[kk], k1f, s1);
      }

      const bool v0 = (kb0 + lr) < klen;
      const bool v1 = (kb0 + 16 + lr) < klen;
      float p0[4], p1[4], pm[4];
#pragma unroll
      for (int r = 0; r < 4; r++) {
        float a = v0 ? s0[r] * scale : -1e30f;
        float b = v1 ? s1[r] * scale : -1e30f;
        p0[r] = a; p1[r] = b;
        pm[r] = fmaxf(a, b);
      }
#pragma unroll
      for (int o = 1; o < 16; o <<= 1) {
#pragma unroll
        for (int r = 0; r < 4; r++) pm[r] = fmaxf(pm[r], __shfl_xor(pm[r], o, 64));
      }
      float alpha[4], rs[4];
#pragma unroll
      for (int r = 0; r < 4; r++) {
        float mn = fmaxf(m[r], pm[r]);
        alpha[r] = __expf(m[r] - mn);
        m[r] = mn;
        p0[r] = __expf(p0[r] - mn);
        p1[r] = __expf(p1[r] - mn);
        rs[r] = p0[r] + p1[r];
      }
#pragma unroll
      for (int o = 1; o < 16; o <<= 1) {
#pragma unroll
        for (int r = 0; r < 4; r++) rs[r] += __shfl_xor(rs[r], o, 64);
      }
#pragma unroll
      for (int r = 0; r < 4; r++) lse[r] = lse[r] * alpha[r] + rs[r];
#pragma unroll
      for (int nb = 0; nb < 8; nb++)
#pragma unroll
        for (int r = 0; r < 4; r++) oacc[nb][r] *= alpha[r];

      // P (C-layout) -> LDS -> A-layout frag
#pragma unroll
      for (int r = 0; r < 4; r++) {
        lP[w][(lg * 4 + r) * 40 + lr] = f2bf(p0[r]);
        lP[w][(lg * 4 + r) * 40 + 16 + lr] = f2bf(p1[r]);
      }
      __syncthreads();

      u16x8 pa = *(const u16x8*)(&lP[w][lr * 40 + lg * 8]);
#pragma unroll
      for (int nb = 0; nb < 8; nb++) {
        u16x8 vf = *(const u16x8*)(&lVt[(nb * 16 + lr) * 40 + lg * 8]);
        oacc[nb] = mfma16(pa, vf, oacc[nb]);
      }
    }

    float inv[4];
#pragma unroll
    for (int r = 0; r < 4; r++) inv[r] = 1.f / lse[r];
#pragma unroll
    for (int nb = 0; nb < 8; nb++)
#pragma unroll
      for (int r = 0; r < 4; r++) osum[nb][r] += oacc[nb][r] * inv[r];
  }

#pragma unroll
  for (int nb = 0; nb < 8; nb++)
#pragma unroll
    for (int r = 0; r < 4; r++)
      out[(long)(q0 + w * 16 + lg * 4 + r) * 1536 + h * 128 + nb * 16 + lr] =
          f2bf(osum[nb][r]);
}

// ---------- launcher ----------
extern "C" void kernel_launch(void* const* d_in, const int* in_sizes, int n_in,
                              void* d_out, int out_size, void* d_ws, size_t ws_size,
                              hipStream_t stream) {
  (void)in_sizes; (void)n_in; (void)out_size; (void)ws_size;
  const float* x    = (const float*)d_in[0];
  const float* ctx  = (const float*)d_in[1];
  const float* aud  = (const float*)d_in[2];
  const float* Wq   = (const float*)d_in[3];
  const float* bq   = (const float*)d_in[4];
  const float* Wk   = (const float*)d_in[5];
  const float* bk   = (const float*)d_in[6];
  const float* Wv   = (const float*)d_in[7];
  const float* bv   = (const float*)d_in[8];
  const float* Wki  = (const float*)d_in[9];
  const float* bki  = (const float*)d_in[10];
  const float* Wvi  = (const float*)d_in[11];
  const float* bvi  = (const float*)d_in[12];
  const float* Wo   = (const float*)d_in[13];
  const float* bo   = (const float*)d_in[14];
  const float* nqw  = (const float*)d_in[15];
  const float* nkw  = (const float*)d_in[16];
  const float* nkiw = (const float*)d_in[17];
  const float* Wkp  = (const float*)d_in[18];
  const float* Wvp  = (const float*)d_in[19];
  const int* clen   = (const int*)d_in[20];
  const int* alens  = (const int*)d_in[21];
  float* out = (float*)d_out;

  char* ws = (char*)d_ws;
  size_t o = 0;
  auto alloc = [&](size_t bytes) { char* p = ws + o; o += bytes; return p; };
  unsigned short* x_bf    = (unsigned short*)alloc(33030144);  // 10752x1536
  unsigned short* ctx_bf  = (unsigned short*)alloc(2362368);   // 769x1536
  unsigned short* aud_bf  = (unsigned short*)alloc(1032192);   // 672x768
  unsigned short* Wq_bf   = (unsigned short*)alloc(4718592);
  unsigned short* Wo_bf   = (unsigned short*)alloc(4718592);
  unsigned short* Wkv_bf  = (unsigned short*)alloc(9437184);   // [Wk;Wv] 3072x1536
  unsigned short* Wkvi_bf = (unsigned short*)alloc(9437184);   // [Wki;Wvi]
  unsigned short* Wkva_bf = (unsigned short*)alloc(4718592);   // [Wkp;Wvp] 3072x768
  float* q_f32   = (float*)alloc(66060288);                    // 10752x1536 f32
  float* kvt_f32 = (float*)alloc(6291456);                     // 512x3072
  float* kvi_f32 = (float*)alloc(3158016);                     // 257x3072
  float* kva_f32 = (float*)alloc(8257536);                     // 672x3072
  unsigned short* q_bf  = (unsigned short*)alloc(33030144);
  unsigned short* kt_bf = (unsigned short*)alloc(1572864);
  unsigned short* vt_bf = (unsigned short*)alloc(1572864);
  unsigned short* ki_bf = (unsigned short*)alloc(789504);
  unsigned short* vi_bf = (unsigned short*)alloc(789504);
  unsigned short* ka_bf = (unsigned short*)alloc(2064384);
  unsigned short* va_bf = (unsigned short*)alloc(2064384);
  unsigned short* attn_bf = x_bf;   // x_bf dead after Q GEMM; attn writes bf16 here

  auto conv = [&](const float* src, unsigned short* dst, int n) {
    int n4 = n >> 2;
    int grid = (n4 + 255) / 256; if (grid > 1024) grid = 1024;
    k_conv<<<grid, 256, 0, stream>>>(src, dst, n4);
  };

  conv(x, x_bf, 10752 * 1536);
  conv(ctx, ctx_bf, 769 * 1536);
  conv(aud, aud_bf, 672 * 768);
  conv(Wq, Wq_bf, 1536 * 1536);
  conv(Wo, Wo_bf, 1536 * 1536);
  conv(Wk, Wkv_bf, 1536 * 1536);
  conv(Wv, Wkv_bf + 1536 * 1536, 1536 * 1536);
  conv(Wki, Wkvi_bf, 1536 * 1536);
  conv(Wvi, Wkvi_bf + 1536 * 1536, 1536 * 1536);
  conv(Wkp, Wkva_bf, 1536 * 768);
  conv(Wvp, Wkva_bf + 1536 * 768, 1536 * 768);

  // projections
  k_gemm<<<dim3(12, 84), 256, 0, stream>>>(x_bf, Wq_bf, q_f32, 10752, 1536, 1536, bq, nullptr);
  k_gemm<<<dim3(24, 4), 256, 0, stream>>>(ctx_bf + 257 * 1536, Wkv_bf, kvt_f32, 512, 3072, 1536, bk, bv);
  k_gemm<<<dim3(24, 3), 256, 0, stream>>>(ctx_bf, Wkvi_bf, kvi_f32, 257, 3072, 1536, bki, bvi);
  k_gemm<<<dim3(24, 6), 256, 0, stream>>>(aud_bf, Wkva_bf, kva_f32, 672, 3072, 768, nullptr, nullptr);

  // norms / bf16 conversion
  k_postproc<true><<<10752, 256, 0, stream>>>(q_f32, 1536, 0, nqw, q_bf);
  k_postproc<true><<<512, 256, 0, stream>>>(kvt_f32, 3072, 0, nkw, kt_bf);
  k_postproc<false><<<512, 256, 0, stream>>>(kvt_f32, 3072, 1536, nullptr, vt_bf);
  k_postproc<true><<<257, 256, 0, stream>>>(kvi_f32, 3072, 0, nkiw, ki_bf);
  k_postproc<false><<<257, 256, 0, stream>>>(kvi_f32, 3072, 1536, nullptr, vi_bf);
  k_postproc<false><<<672, 256, 0, stream>>>(kva_f32, 3072, 0, nullptr, ka_bf);
  k_postproc<false><<<672, 256, 0, stream>>>(kva_f32, 3072, 1536, nullptr, va_bf);

  // fused img+txt+audio attention, writes summed context directly as bf16
  k_attn<<<dim3(168, 12), 256, 0, stream>>>(q_bf, kt_bf, vt_bf, ki_bf, vi_bf, ka_bf, va_bf,
                                            clen, alens, attn_bf);

  // output projection
  k_gemm<<<dim3(12, 84), 256, 0, stream>>>(attn_bf, Wo_bf, out, 10752, 1536, 1536, bo, nullptr);
}

// Round 4
// 735.117 us; speedup vs baseline: 1.0649x; 1.0569x over previous
//
#include <hip/hip_runtime.h>

// ---------- types ----------
typedef __bf16 bf16x8 __attribute__((ext_vector_type(8)));
typedef unsigned short u16x8 __attribute__((ext_vector_type(8)));
typedef float f32x4 __attribute__((ext_vector_type(4)));

__device__ __forceinline__ unsigned short f2bf(float f) {
  unsigned u = __builtin_bit_cast(unsigned, f);
  u += 0x7FFFu + ((u >> 16) & 1u);   // round-to-nearest-even
  return (unsigned short)(u >> 16);
}

__device__ __forceinline__ f32x4 mfma16(u16x8 a, u16x8 b, f32x4 c) {
  return __builtin_amdgcn_mfma_f32_16x16x32_bf16(
      __builtin_bit_cast(bf16x8, a), __builtin_bit_cast(bf16x8, b), c, 0, 0, 0);
}

// async global->LDS, 16B per lane; LDS dest is wave-uniform base + lane*16
#define GLD16(gp, lp)                                                              \
  __builtin_amdgcn_global_load_lds((const __attribute__((address_space(1))) void*)(gp), \
                                   (__attribute__((address_space(3))) void*)(lp), 16, 0, 0)

// ---------- f32 -> bf16 convert ----------
__global__ __launch_bounds__(256) void k_conv(const float* __restrict__ src,
                                              unsigned short* __restrict__ dst, int n4) {
  int i = blockIdx.x * 256 + threadIdx.x;
  int stride = gridDim.x * 256;
  for (; i < n4; i += stride) {
    float4 v = ((const float4*)src)[i];
    ushort4 o;
    o.x = f2bf(v.x); o.y = f2bf(v.y); o.z = f2bf(v.z); o.w = f2bf(v.w);
    ((ushort4*)dst)[i] = o;
  }
}

// ---------- GEMM: C[M,N] = A[M,K]bf16 * B[N,K]^T bf16 + bias ----------
// 128x128 tile, BK=32, 4 waves (2x2). m97 structure (global_load_lds staging).
// Epilogue: cols<1536 -> f32 buffer (Cf) or direct bf16 (CKbf);
//           cols>=1536 -> bf16 scatter to V^T layout [h][d][NK] (frame-major if NK==32).
__global__ __launch_bounds__(256) void k_gemm(const unsigned short* __restrict__ A,
                                              const unsigned short* __restrict__ B,
                                              float* __restrict__ Cf,
                                              unsigned short* __restrict__ CKbf,
                                              unsigned short* __restrict__ CVT, int NK,
                                              int M, int N, int K,
                                              const float* __restrict__ bias0,
                                              const float* __restrict__ bias1) {
  __shared__ unsigned short lA[128 * 32];  // linear row-major [128][32]
  __shared__ unsigned short lB[128 * 32];
  const int tid = threadIdx.x;
  const int l = tid & 63, w = tid >> 6;
  const int wm = w >> 1, wn = w & 1;
  const int lr = l & 15, lg = l >> 4;
  const int m0 = blockIdx.y * 128, n0 = blockIdx.x * 128;

  const int srow = w * 16 + (l >> 2);
  const int sk8 = (l & 3) * 8;
  int raA0 = m0 + srow;       if (raA0 >= M) raA0 = M - 1;
  int raA1 = m0 + 64 + srow;  if (raA1 >= M) raA1 = M - 1;
  const long rbB0 = (long)(n0 + srow) * K;
  const long rbB1 = (long)(n0 + 64 + srow) * K;
  const long raA0o = (long)raA0 * K, raA1o = (long)raA1 * K;
  unsigned short* ldsA0 = &lA[(w * 16) * 32];
  unsigned short* ldsA1 = &lA[(64 + w * 16) * 32];
  unsigned short* ldsB0 = &lB[(w * 16) * 32];
  unsigned short* ldsB1 = &lB[(64 + w * 16) * 32];

  const f32x4 zero4 = {0.f, 0.f, 0.f, 0.f};
  f32x4 acc[4][4];
#pragma unroll
  for (int i = 0; i < 4; i++)
#pragma unroll
    for (int j = 0; j < 4; j++) acc[i][j] = zero4;

  for (int k0 = 0; k0 < K; k0 += 32) {
    __syncthreads();
    GLD16(A + raA0o + k0 + sk8, ldsA0);
    GLD16(A + raA1o + k0 + sk8, ldsA1);
    GLD16(B + rbB0 + k0 + sk8, ldsB0);
    GLD16(B + rbB1 + k0 + sk8, ldsB1);
    __syncthreads();

    u16x8 af[4], bfr[4];
#pragma unroll
    for (int mb = 0; mb < 4; mb++)
      af[mb] = *(const u16x8*)(&lA[(wm * 64 + mb * 16 + lr) * 32 + lg * 8]);
#pragma unroll
    for (int nb = 0; nb < 4; nb++)
      bfr[nb] = *(const u16x8*)(&lB[(wn * 64 + nb * 16 + lr) * 32 + lg * 8]);
#pragma unroll
    for (int mb = 0; mb < 4; mb++)
#pragma unroll
      for (int nb = 0; nb < 4; nb++) acc[mb][nb] = mfma16(af[mb], bfr[nb], acc[mb][nb]);
  }

#pragma unroll
  for (int mb = 0; mb < 4; mb++)
#pragma unroll
    for (int nb = 0; nb < 4; nb++)
#pragma unroll
      for (int r = 0; r < 4; r++) {
        int row = m0 + wm * 64 + mb * 16 + lg * 4 + r;
        if (row < M) {
          int col = n0 + wn * 64 + nb * 16 + lr;
          float b = 0.f;
          if (col < 1536) { if (bias0) b = bias0[col]; }
          else            { if (bias1) b = bias1[col - 1536]; }
          float val = acc[mb][nb][r] + b;
          if (col < 1536) {
            if (CKbf) CKbf[(long)row * 1536 + col] = f2bf(val);
            else      Cf[(long)row * 1536 + col] = val;
          } else {
            int c2 = col - 1536, hh = c2 >> 7, dd = c2 & 127;
            long addr = (NK == 32)
                ? ((((long)(row >> 5) * 12 + hh) * 128 + dd) * 32 + (row & 31))
                : (((long)hh * 128 + dd) * NK + row);
            CVT[addr] = f2bf(val);
          }
        }
      }
}

// ---------- per-row RMSNorm over 1536 cols, f32->bf16 ----------
__global__ __launch_bounds__(256) void k_postproc(const float* __restrict__ src,
                                                  const float* __restrict__ w,
                                                  unsigned short* __restrict__ dst) {
  const int row = blockIdx.x;
  const float* s = src + (long)row * 1536;
  float v[6];
  float ss = 0.f;
#pragma unroll
  for (int i = 0; i < 6; i++) {
    v[i] = s[threadIdx.x + i * 256];
    ss += v[i] * v[i];
  }
#pragma unroll
  for (int o = 1; o < 64; o <<= 1) ss += __shfl_xor(ss, o, 64);
  __shared__ float red[4];
  if ((threadIdx.x & 63) == 0) red[threadIdx.x >> 6] = ss;
  __syncthreads();
  float tot = red[0] + red[1] + red[2] + red[3];
  float scale = rsqrtf(tot * (1.f / 1536.f) + 1e-6f);
  unsigned short* d = dst + (long)row * 1536;
#pragma unroll
  for (int i = 0; i < 6; i++)
    d[threadIdx.x + i * 256] = f2bf(v[i] * scale * w[threadIdx.x + i * 256]);
}

// ---------- fused 3-way flash attention ----------
// grid (168 q-tiles of 64, 12 heads), 4 waves x 16 q-rows.
// K LDS: [32 key][128 d] linear, XOR-swizzled via pre-swizzled global source.
// V LDS: V^T [128 d][32 key] linear (from global V^T), conflict-free b128 reads.
// Double-buffered global_load_lds staging, counted vmcnt, 2 barriers/tile.
__global__ __launch_bounds__(256) void k_attn(
    const unsigned short* __restrict__ qb, const unsigned short* __restrict__ kt,
    const unsigned short* __restrict__ vtT, const unsigned short* __restrict__ ki,
    const unsigned short* __restrict__ viT, const unsigned short* __restrict__ ka,
    const unsigned short* __restrict__ vaT, const int* __restrict__ clen_p,
    const int* __restrict__ alens, unsigned short* __restrict__ out) {
  __shared__ unsigned short lK[2][32 * 128];   // 8KB per buffer
  __shared__ unsigned short lV[2][128 * 32];   // 8KB per buffer
  __shared__ unsigned short lP[4][16 * 40];    // per-wave P transpose

  const int qt = blockIdx.x, h = blockIdx.y;
  const int tid = threadIdx.x, l = tid & 63, w = tid >> 6;
  const int lr = l & 15, lg = l >> 4;
  const int q0 = qt * 64;
  const int frame = qt >> 3;
  const float scale = 0.08838834764831845f;  // 1/sqrt(128)

  u16x8 qf[4];
  {
    const unsigned short* qp = qb + (long)(q0 + w * 16 + lr) * 1536 + h * 128;
#pragma unroll
    for (int kk = 0; kk < 4; kk++) qf[kk] = *(const u16x8*)(qp + kk * 32 + lg * 8);
  }

  const f32x4 zero4 = {0.f, 0.f, 0.f, 0.f};
  f32x4 osum[8];
#pragma unroll
  for (int nb = 0; nb < 8; nb++) osum[nb] = zero4;

  for (int ph = 0; ph < 3; ph++) {
    const unsigned short *kp, *vtp;
    int nk, klen, NK;
    if (ph == 0) {
      kp = ki; vtp = viT + (long)h * 128 * 288; nk = 257; klen = 257; NK = 288;
    } else if (ph == 1) {
      kp = kt; vtp = vtT + (long)h * 128 * 512; nk = 512; klen = clen_p[0]; NK = 512;
    } else {
      kp = ka + (long)frame * 32 * 1536;
      vtp = vaT + (long)frame * 49152 + h * 4096;
      nk = 32; klen = alens[frame]; NK = 32;
    }

    // staging: 4 GLD16/thread. K: slot=(i*256+tid): key=slot>>4, chunk=slot&15,
    // src chunk pre-swizzled (c^(key&7)) so swizzled read is conflict-free.
    // V: d=slot>>2, keychunk=slot&3 from global V^T.
    auto stage = [&](int kb0, int b) {
      unsigned short* lKb = &lK[b][0];
      unsigned short* lVb = &lV[b][0];
#pragma unroll
      for (int i = 0; i < 2; i++) {
        int slot = tid + i * 256;
        int key = slot >> 4, c16 = slot & 15;
        int gk = kb0 + key; gk = gk < nk ? gk : nk - 1;
        GLD16(kp + (long)gk * 1536 + h * 128 + ((c16 ^ (key & 7)) * 8),
              lKb + (i * 256 + w * 64) * 8);
        int d = slot >> 2, kc = slot & 3;
        GLD16(vtp + (long)d * NK + kb0 + kc * 8, lVb + (i * 256 + w * 64) * 8);
      }
    };

    float m[4], lse[4];
#pragma unroll
    for (int r = 0; r < 4; r++) { m[r] = -1e30f; lse[r] = 0.f; }
    f32x4 oacc[8];
#pragma unroll
    for (int nb = 0; nb < 8; nb++) oacc[nb] = zero4;

    const int nt = (klen + 31) >> 5;
    stage(0, 0);
    int cur = 0;
    for (int t = 0; t < nt; t++) {
      const int kb0 = t * 32;
      if (t + 1 < nt) {
        stage(kb0 + 32, cur ^ 1);
        __builtin_amdgcn_sched_barrier(0);
        asm volatile("s_waitcnt vmcnt(4)" ::: "memory");
      } else {
        __builtin_amdgcn_sched_barrier(0);
        asm volatile("s_waitcnt vmcnt(0)" ::: "memory");
      }
      __builtin_amdgcn_sched_barrier(0);
      __builtin_amdgcn_s_barrier();   // current tile visible to all waves

      const unsigned short* lKc = &lK[cur][0];
      const unsigned short* lVc = &lV[cur][0];

      // S = Q(16x128) * K^T(128x32), swizzled K reads (conflict-free)
      f32x4 s0 = zero4, s1 = zero4;
#pragma unroll
      for (int kk = 0; kk < 4; kk++) {
        int c = (kk * 4 + lg) ^ (lr & 7);
        u16x8 k0f = *(const u16x8*)(lKc + lr * 128 + c * 8);
        u16x8 k1f = *(const u16x8*)(lKc + (16 + lr) * 128 + c * 8);
        s0 = mfma16(qf[kk], k0f, s0);
        s1 = mfma16(qf[kk], k1f, s1);
      }

      const bool v0 = (kb0 + lr) < klen;
      const bool v1 = (kb0 + 16 + lr) < klen;
      float p0[4], p1[4], pm[4];
#pragma unroll
      for (int r = 0; r < 4; r++) {
        float a = v0 ? s0[r] * scale : -1e30f;
        float b = v1 ? s1[r] * scale : -1e30f;
        p0[r] = a; p1[r] = b;
        pm[r] = fmaxf(a, b);
      }
#pragma unroll
      for (int o = 1; o < 16; o <<= 1) {
#pragma unroll
        for (int r = 0; r < 4; r++) pm[r] = fmaxf(pm[r], __shfl_xor(pm[r], o, 64));
      }
      // T13 defer-max: only rescale when max grew by > 8
      bool grow = (pm[0] > m[0] + 8.f) || (pm[1] > m[1] + 8.f) ||
                  (pm[2] > m[2] + 8.f) || (pm[3] > m[3] + 8.f);
      if (__any(grow)) {
#pragma unroll
        for (int r = 0; r < 4; r++) {
          float mn = fmaxf(m[r], pm[r]);
          float alpha = __expf(m[r] - mn);
          m[r] = mn;
          lse[r] *= alpha;
#pragma unroll
          for (int nb = 0; nb < 8; nb++) oacc[nb][r] *= alpha;
        }
      }
      float rs[4];
#pragma unroll
      for (int r = 0; r < 4; r++) {
        p0[r] = __expf(p0[r] - m[r]);
        p1[r] = __expf(p1[r] - m[r]);
        rs[r] = p0[r] + p1[r];
      }
#pragma unroll
      for (int o = 1; o < 16; o <<= 1) {
#pragma unroll
        for (int r = 0; r < 4; r++) rs[r] += __shfl_xor(rs[r], o, 64);
      }
#pragma unroll
      for (int r = 0; r < 4; r++) lse[r] += rs[r];

      // P (C-layout) -> per-wave LDS -> A-layout frag
#pragma unroll
      for (int r = 0; r < 4; r++) {
        lP[w][(lg * 4 + r) * 40 + lr] = f2bf(p0[r]);
        lP[w][(lg * 4 + r) * 40 + 16 + lr] = f2bf(p1[r]);
      }
      u16x8 pa = *(const u16x8*)(&lP[w][lr * 40 + lg * 8]);
#pragma unroll
      for (int nb = 0; nb < 8; nb++) {
        u16x8 vf = *(const u16x8*)(lVc + (nb * 16 + lr) * 32 + lg * 8);
        oacc[nb] = mfma16(pa, vf, oacc[nb]);
      }

      __builtin_amdgcn_s_barrier();   // readers done before next issue overwrites
      cur ^= 1;
    }

    float inv[4];
#pragma unroll
    for (int r = 0; r < 4; r++) inv[r] = 1.f / lse[r];
#pragma unroll
    for (int nb = 0; nb < 8; nb++)
#pragma unroll
      for (int r = 0; r < 4; r++) osum[nb][r] += oacc[nb][r] * inv[r];
  }

#pragma unroll
  for (int nb = 0; nb < 8; nb++)
#pragma unroll
    for (int r = 0; r < 4; r++)
      out[(long)(q0 + w * 16 + lg * 4 + r) * 1536 + h * 128 + nb * 16 + lr] =
          f2bf(osum[nb][r]);
}

// ---------- launcher ----------
extern "C" void kernel_launch(void* const* d_in, const int* in_sizes, int n_in,
                              void* d_out, int out_size, void* d_ws, size_t ws_size,
                              hipStream_t stream) {
  (void)in_sizes; (void)n_in; (void)out_size; (void)ws_size;
  const float* x    = (const float*)d_in[0];
  const float* ctx  = (const float*)d_in[1];
  const float* aud  = (const float*)d_in[2];
  const float* Wq   = (const float*)d_in[3];
  const float* bq   = (const float*)d_in[4];
  const float* Wk   = (const float*)d_in[5];
  const float* bk   = (const float*)d_in[6];
  const float* Wv   = (const float*)d_in[7];
  const float* bv   = (const float*)d_in[8];
  const float* Wki  = (const float*)d_in[9];
  const float* bki  = (const float*)d_in[10];
  const float* Wvi  = (const float*)d_in[11];
  const float* bvi  = (const float*)d_in[12];
  const float* Wo   = (const float*)d_in[13];
  const float* bo   = (const float*)d_in[14];
  const float* nqw  = (const float*)d_in[15];
  const float* nkw  = (const float*)d_in[16];
  const float* nkiw = (const float*)d_in[17];
  const float* Wkp  = (const float*)d_in[18];
  const float* Wvp  = (const float*)d_in[19];
  const int* clen   = (const int*)d_in[20];
  const int* alens  = (const int*)d_in[21];
  float* out = (float*)d_out;

  char* ws = (char*)d_ws;
  size_t o = 0;
  auto alloc = [&](size_t bytes) { char* p = ws + o; o += bytes; return p; };
  unsigned short* x_bf    = (unsigned short*)alloc(33030144);  // 10752x1536
  unsigned short* ctx_bf  = (unsigned short*)alloc(2362368);   // 769x1536
  unsigned short* aud_bf  = (unsigned short*)alloc(1032192);   // 672x768
  unsigned short* Wq_bf   = (unsigned short*)alloc(4718592);
  unsigned short* Wo_bf   = (unsigned short*)alloc(4718592);
  unsigned short* Wkv_bf  = (unsigned short*)alloc(9437184);   // [Wk;Wv] 3072x1536
  unsigned short* Wkvi_bf = (unsigned short*)alloc(9437184);   // [Wki;Wvi]
  unsigned short* Wkva_bf = (unsigned short*)alloc(4718592);   // [Wkp;Wvp] 3072x768
  float* q_f32   = (float*)alloc(66060288);                    // 10752x1536 f32
  float* kvt_f32 = (float*)alloc(3145728);                     // 512x1536 (K half)
  float* kvi_f32 = (float*)alloc(1579008);                     // 257x1536 (K half)
  unsigned short* q_bf  = (unsigned short*)alloc(33030144);
  unsigned short* kt_bf = (unsigned short*)alloc(1572864);     // 512x1536
  unsigned short* ki_bf = (unsigned short*)alloc(789504);      // 257x1536
  unsigned short* ka_bf = (unsigned short*)alloc(2064384);     // 672x1536
  unsigned short* vtT   = (unsigned short*)alloc(1572864);     // [12][128][512]
  unsigned short* viT   = (unsigned short*)alloc(884736);      // [12][128][288] (pad)
  unsigned short* vaT   = (unsigned short*)alloc(2064384);     // [21][12][128][32]
  unsigned short* attn_bf = x_bf;   // x_bf dead after Q GEMM

  auto conv = [&](const float* src, unsigned short* dst, int n) {
    int n4 = n >> 2;
    int grid = (n4 + 255) / 256; if (grid > 1024) grid = 1024;
    k_conv<<<grid, 256, 0, stream>>>(src, dst, n4);
  };

  conv(x, x_bf, 10752 * 1536);
  conv(ctx, ctx_bf, 769 * 1536);
  conv(aud, aud_bf, 672 * 768);
  conv(Wq, Wq_bf, 1536 * 1536);
  conv(Wo, Wo_bf, 1536 * 1536);
  conv(Wk, Wkv_bf, 1536 * 1536);
  conv(Wv, Wkv_bf + 1536 * 1536, 1536 * 1536);
  conv(Wki, Wkvi_bf, 1536 * 1536);
  conv(Wvi, Wkvi_bf + 1536 * 1536, 1536 * 1536);
  conv(Wkp, Wkva_bf, 1536 * 768);
  conv(Wvp, Wkva_bf + 1536 * 768, 1536 * 768);

  // projections (KV GEMMs scatter V^T + audio-K directly as bf16)
  k_gemm<<<dim3(12, 84), 256, 0, stream>>>(x_bf, Wq_bf, q_f32, nullptr, nullptr, 0,
                                           10752, 1536, 1536, bq, nullptr);
  k_gemm<<<dim3(24, 4), 256, 0, stream>>>(ctx_bf + 257 * 1536, Wkv_bf, kvt_f32, nullptr,
                                          vtT, 512, 512, 3072, 1536, bk, bv);
  k_gemm<<<dim3(24, 3), 256, 0, stream>>>(ctx_bf, Wkvi_bf, kvi_f32, nullptr,
                                          viT, 288, 257, 3072, 1536, bki, bvi);
  k_gemm<<<dim3(24, 6), 256, 0, stream>>>(aud_bf, Wkva_bf, nullptr, ka_bf,
                                          vaT, 32, 672, 3072, 768, nullptr, nullptr);

  // RMSNorm + bf16
  k_postproc<<<10752, 256, 0, stream>>>(q_f32, nqw, q_bf);
  k_postproc<<<512, 256, 0, stream>>>(kvt_f32, nkw, kt_bf);
  k_postproc<<<257, 256, 0, stream>>>(kvi_f32, nkiw, ki_bf);

  // fused img+txt+audio attention -> bf16
  k_attn<<<dim3(168, 12), 256, 0, stream>>>(q_bf, kt_bf, vtT, ki_bf, viT, ka_bf, vaT,
                                            clen, alens, attn_bf);

  // output projection
  k_gemm<<<dim3(12, 84), 256, 0, stream>>>(attn_bf, Wo_bf, out, nullptr, nullptr, 0,
                                           10752, 1536, 1536, bo, nullptr);
}

// Round 5
// 716.018 us; speedup vs baseline: 1.0934x; 1.0267x over previous
//
#include <hip/hip_runtime.h>

// ---------- types ----------
typedef __bf16 bf16x8 __attribute__((ext_vector_type(8)));
typedef unsigned short u16x8 __attribute__((ext_vector_type(8)));
typedef float f32x4 __attribute__((ext_vector_type(4)));

__device__ __forceinline__ unsigned short f2bf(float f) {
  __bf16 b = (__bf16)f;                     // native RNE cvt
  return __builtin_bit_cast(unsigned short, b);
}

__device__ __forceinline__ f32x4 mfma16(u16x8 a, u16x8 b, f32x4 c) {
  return __builtin_amdgcn_mfma_f32_16x16x32_bf16(
      __builtin_bit_cast(bf16x8, a), __builtin_bit_cast(bf16x8, b), c, 0, 0, 0);
}

// async global->LDS, 16B per lane; LDS dest is wave-uniform base + lane*16
#define GLD16(gp, lp)                                                              \
  __builtin_amdgcn_global_load_lds((const __attribute__((address_space(1))) void*)(gp), \
                                   (__attribute__((address_space(3))) void*)(lp), 16, 0, 0)

// ---------- batched f32 -> bf16 convert (one launch for all tensors) ----------
struct CJobs {
  const float* s[11];
  unsigned short* d[11];
  int n4[11];
};
__global__ __launch_bounds__(256) void k_convN(CJobs j) {
  const int job = blockIdx.y;
  const int n4 = j.n4[job];
  const float* __restrict__ src = j.s[job];
  unsigned short* __restrict__ dst = j.d[job];
  for (int i = blockIdx.x * 256 + threadIdx.x; i < n4; i += gridDim.x * 256) {
    float4 v = ((const float4*)src)[i];
    ushort4 o;
    o.x = f2bf(v.x); o.y = f2bf(v.y); o.z = f2bf(v.z); o.w = f2bf(v.w);
    ((ushort4*)dst)[i] = o;
  }
}

// ---------- GEMM: C[M,N] = A[M,K]bf16 * B[N,K]^T bf16 + bias ----------
// 128x128 tile, BK=32, 4 waves (2x2). m97 structure (global_load_lds staging).
// Epilogue: cols<1536 -> f32 buffer (Cf) or direct bf16 (CKbf);
//           cols>=1536 -> bf16 scatter to V^T layout [h][d][NK] (frame-major if NK==32).
__global__ __launch_bounds__(256) void k_gemm(const unsigned short* __restrict__ A,
                                              const unsigned short* __restrict__ B,
                                              float* __restrict__ Cf,
                                              unsigned short* __restrict__ CKbf,
                                              unsigned short* __restrict__ CVT, int NK,
                                              int M, int N, int K,
                                              const float* __restrict__ bias0,
                                              const float* __restrict__ bias1) {
  __shared__ unsigned short lA[128 * 32];  // linear row-major [128][32]
  __shared__ unsigned short lB[128 * 32];
  const int tid = threadIdx.x;
  const int l = tid & 63, w = tid >> 6;
  const int wm = w >> 1, wn = w & 1;
  const int lr = l & 15, lg = l >> 4;
  const int m0 = blockIdx.y * 128, n0 = blockIdx.x * 128;

  const int srow = w * 16 + (l >> 2);
  const int sk8 = (l & 3) * 8;
  int raA0 = m0 + srow;       if (raA0 >= M) raA0 = M - 1;
  int raA1 = m0 + 64 + srow;  if (raA1 >= M) raA1 = M - 1;
  const long rbB0 = (long)(n0 + srow) * K;
  const long rbB1 = (long)(n0 + 64 + srow) * K;
  const long raA0o = (long)raA0 * K, raA1o = (long)raA1 * K;
  unsigned short* ldsA0 = &lA[(w * 16) * 32];
  unsigned short* ldsA1 = &lA[(64 + w * 16) * 32];
  unsigned short* ldsB0 = &lB[(w * 16) * 32];
  unsigned short* ldsB1 = &lB[(64 + w * 16) * 32];

  const f32x4 zero4 = {0.f, 0.f, 0.f, 0.f};
  f32x4 acc[4][4];
#pragma unroll
  for (int i = 0; i < 4; i++)
#pragma unroll
    for (int j = 0; j < 4; j++) acc[i][j] = zero4;

  for (int k0 = 0; k0 < K; k0 += 32) {
    __syncthreads();
    GLD16(A + raA0o + k0 + sk8, ldsA0);
    GLD16(A + raA1o + k0 + sk8, ldsA1);
    GLD16(B + rbB0 + k0 + sk8, ldsB0);
    GLD16(B + rbB1 + k0 + sk8, ldsB1);
    __syncthreads();

    u16x8 af[4], bfr[4];
#pragma unroll
    for (int mb = 0; mb < 4; mb++)
      af[mb] = *(const u16x8*)(&lA[(wm * 64 + mb * 16 + lr) * 32 + lg * 8]);
#pragma unroll
    for (int nb = 0; nb < 4; nb++)
      bfr[nb] = *(const u16x8*)(&lB[(wn * 64 + nb * 16 + lr) * 32 + lg * 8]);
#pragma unroll
    for (int mb = 0; mb < 4; mb++)
#pragma unroll
      for (int nb = 0; nb < 4; nb++) acc[mb][nb] = mfma16(af[mb], bfr[nb], acc[mb][nb]);
  }

#pragma unroll
  for (int mb = 0; mb < 4; mb++)
#pragma unroll
    for (int nb = 0; nb < 4; nb++)
#pragma unroll
      for (int r = 0; r < 4; r++) {
        int row = m0 + wm * 64 + mb * 16 + lg * 4 + r;
        if (row < M) {
          int col = n0 + wn * 64 + nb * 16 + lr;
          float b = 0.f;
          if (col < 1536) { if (bias0) b = bias0[col]; }
          else            { if (bias1) b = bias1[col - 1536]; }
          float val = acc[mb][nb][r] + b;
          if (col < 1536) {
            if (CKbf) CKbf[(long)row * 1536 + col] = f2bf(val);
            else      Cf[(long)row * 1536 + col] = val;
          } else {
            int c2 = col - 1536, hh = c2 >> 7, dd = c2 & 127;
            long addr = (NK == 32)
                ? ((((long)(row >> 5) * 12 + hh) * 128 + dd) * 32 + (row & 31))
                : (((long)hh * 128 + dd) * NK + row);
            CVT[addr] = f2bf(val);
          }
        }
      }
}

// ---------- per-row RMSNorm over 1536 cols, f32->bf16 (w scaled by pscale) ----------
__global__ __launch_bounds__(256) void k_postproc(const float* __restrict__ src,
                                                  const float* __restrict__ w,
                                                  unsigned short* __restrict__ dst,
                                                  float pscale) {
  const int row = blockIdx.x;
  const float* s = src + (long)row * 1536;
  float v[6];
  float ss = 0.f;
#pragma unroll
  for (int i = 0; i < 6; i++) {
    v[i] = s[threadIdx.x + i * 256];
    ss += v[i] * v[i];
  }
#pragma unroll
  for (int o = 1; o < 64; o <<= 1) ss += __shfl_xor(ss, o, 64);
  __shared__ float red[4];
  if ((threadIdx.x & 63) == 0) red[threadIdx.x >> 6] = ss;
  __syncthreads();
  float tot = red[0] + red[1] + red[2] + red[3];
  float scale = rsqrtf(tot * (1.f / 1536.f) + 1e-6f) * pscale;
  unsigned short* d = dst + (long)row * 1536;
#pragma unroll
  for (int i = 0; i < 6; i++)
    d[threadIdx.x + i * 256] = f2bf(v[i] * scale * w[threadIdx.x + i * 256]);
}

// ---------- fused 3-way flash attention ----------
// grid (168 q-tiles of 64, 12 heads), 4 waves x 16 q-rows.
// Q pre-scaled by 1/sqrt(128) in its RMSNorm. K buffers padded to 32-key multiples
// (no clamps); garbage keys masked before exp. Pointer-increment staging.
__global__ __launch_bounds__(256) void k_attn(
    const unsigned short* __restrict__ qb, const unsigned short* __restrict__ kt,
    const unsigned short* __restrict__ vtT, const unsigned short* __restrict__ ki,
    const unsigned short* __restrict__ viT, const unsigned short* __restrict__ ka,
    const unsigned short* __restrict__ vaT, const int* __restrict__ clen_p,
    const int* __restrict__ alens, unsigned short* __restrict__ out) {
  __shared__ unsigned short lK[2][32 * 128];   // 8KB per buffer
  __shared__ unsigned short lV[2][128 * 32];   // 8KB per buffer
  __shared__ unsigned short lP[4][16 * 40];    // per-wave P transpose

  const int qt = blockIdx.x, h = blockIdx.y;
  const int tid = threadIdx.x, l = tid & 63, w = tid >> 6;
  const int lr = l & 15, lg = l >> 4;
  const int q0 = qt * 64;
  const int frame = qt >> 3;

  // staging lane constants
  const int key0 = tid >> 4;                    // 0..15 (i=1 adds 16)
  const int swc8 = ((tid & 15) ^ (key0 & 7)) * 8;  // pre-swizzled K chunk
  const int d0 = tid >> 2;                      // 0..63 (i=1 adds 64)
  const int kc8 = (tid & 3) * 8;

  u16x8 qf[4];
  {
    const unsigned short* qp = qb + (long)(q0 + w * 16 + lr) * 1536 + h * 128;
#pragma unroll
    for (int kk = 0; kk < 4; kk++) qf[kk] = *(const u16x8*)(qp + kk * 32 + lg * 8);
  }

  const f32x4 zero4 = {0.f, 0.f, 0.f, 0.f};
  f32x4 osum[8];
#pragma unroll
  for (int nb = 0; nb < 8; nb++) osum[nb] = zero4;

  for (int ph = 0; ph < 3; ph++) {
    const unsigned short *kp, *vtp;
    int klen, NK;
    if (ph == 0) {
      kp = ki; vtp = viT + (long)h * 128 * 288; klen = 257; NK = 288;
    } else if (ph == 1) {
      kp = kt; vtp = vtT + (long)h * 128 * 512; klen = clen_p[0]; NK = 512;
    } else {
      kp = ka + (long)frame * 32 * 1536;
      vtp = vaT + (long)frame * 49152 + h * 4096;
      klen = alens[frame]; NK = 32;
    }

    // running staging pointers (advance by one 32-key tile each stage)
    const unsigned short* pk0 = kp + (long)key0 * 1536 + h * 128 + swc8;
    const unsigned short* pk1 = pk0 + 16 * 1536;
    const unsigned short* pv0 = vtp + (long)d0 * NK + kc8;
    const unsigned short* pv1 = pv0 + (long)64 * NK;

    float m[4], lse[4];
#pragma unroll
    for (int r = 0; r < 4; r++) { m[r] = -1e30f; lse[r] = 0.f; }
    f32x4 oacc[8];
#pragma unroll
    for (int nb = 0; nb < 8; nb++) oacc[nb] = zero4;

    const int nt = (klen + 31) >> 5;

    // stage tile 0 into buffer 0
    GLD16(pk0, &lK[0][(w * 64) * 8]);
    GLD16(pk1, &lK[0][(256 + w * 64) * 8]);
    GLD16(pv0, &lV[0][(w * 64) * 8]);
    GLD16(pv1, &lV[0][(256 + w * 64) * 8]);
    pk0 += 32 * 1536; pk1 += 32 * 1536; pv0 += 32; pv1 += 32;

    int cur = 0;
    for (int t = 0; t < nt; t++) {
      const int kb0 = t * 32;
      if (t + 1 < nt) {
        const int b = cur ^ 1;
        GLD16(pk0, &lK[b][(w * 64) * 8]);
        GLD16(pk1, &lK[b][(256 + w * 64) * 8]);
        GLD16(pv0, &lV[b][(w * 64) * 8]);
        GLD16(pv1, &lV[b][(256 + w * 64) * 8]);
        pk0 += 32 * 1536; pk1 += 32 * 1536; pv0 += 32; pv1 += 32;
        __builtin_amdgcn_sched_barrier(0);
        asm volatile("s_waitcnt vmcnt(4)" ::: "memory");
      } else {
        __builtin_amdgcn_sched_barrier(0);
        asm volatile("s_waitcnt vmcnt(0)" ::: "memory");
      }
      __builtin_amdgcn_sched_barrier(0);
      __builtin_amdgcn_s_barrier();   // current tile visible to all waves

      const unsigned short* lKc = &lK[cur][0];
      const unsigned short* lVc = &lV[cur][0];

      // S = Q(16x128) * K^T(128x32), swizzled K reads (conflict-free)
      f32x4 s0 = zero4, s1 = zero4;
#pragma unroll
      for (int kk = 0; kk < 4; kk++) {
        int c = (kk * 4 + lg) ^ (lr & 7);
        u16x8 k0f = *(const u16x8*)(lKc + lr * 128 + c * 8);
        u16x8 k1f = *(const u16x8*)(lKc + (16 + lr) * 128 + c * 8);
        s0 = mfma16(qf[kk], k0f, s0);
        s1 = mfma16(qf[kk], k1f, s1);
      }

      float p0[4], p1[4], pm[4];
      if (kb0 + 32 <= klen) {            // interior tile: no masking
#pragma unroll
        for (int r = 0; r < 4; r++) {
          p0[r] = s0[r]; p1[r] = s1[r];
          pm[r] = fmaxf(p0[r], p1[r]);
        }
      } else {                            // boundary tile
        const bool v0 = (kb0 + lr) < klen;
        const bool v1 = (kb0 + 16 + lr) < klen;
#pragma unroll
        for (int r = 0; r < 4; r++) {
          p0[r] = v0 ? s0[r] : -1e30f;
          p1[r] = v1 ? s1[r] : -1e30f;
          pm[r] = fmaxf(p0[r], p1[r]);
        }
      }
#pragma unroll
      for (int o = 1; o < 16; o <<= 1) {
#pragma unroll
        for (int r = 0; r < 4; r++) pm[r] = fmaxf(pm[r], __shfl_xor(pm[r], o, 64));
      }
      // T13 defer-max: only rescale when max grew by > 8
      bool grow = (pm[0] > m[0] + 8.f) || (pm[1] > m[1] + 8.f) ||
                  (pm[2] > m[2] + 8.f) || (pm[3] > m[3] + 8.f);
      if (__any(grow)) {
#pragma unroll
        for (int r = 0; r < 4; r++) {
          float mn = fmaxf(m[r], pm[r]);
          float alpha = __expf(m[r] - mn);
          m[r] = mn;
          lse[r] *= alpha;
#pragma unroll
          for (int nb = 0; nb < 8; nb++) oacc[nb][r] *= alpha;
        }
      }
      float rs[4];
#pragma unroll
      for (int r = 0; r < 4; r++) {
        p0[r] = __expf(p0[r] - m[r]);
        p1[r] = __expf(p1[r] - m[r]);
        rs[r] = p0[r] + p1[r];
      }
#pragma unroll
      for (int o = 1; o < 16; o <<= 1) {
#pragma unroll
        for (int r = 0; r < 4; r++) rs[r] += __shfl_xor(rs[r], o, 64);
      }
#pragma unroll
      for (int r = 0; r < 4; r++) lse[r] += rs[r];

      // P (C-layout) -> per-wave LDS -> A-layout frag
#pragma unroll
      for (int r = 0; r < 4; r++) {
        lP[w][(lg * 4 + r) * 40 + lr] = f2bf(p0[r]);
        lP[w][(lg * 4 + r) * 40 + 16 + lr] = f2bf(p1[r]);
      }
      u16x8 pa = *(const u16x8*)(&lP[w][lr * 40 + lg * 8]);
#pragma unroll
      for (int nb = 0; nb < 8; nb++) {
        u16x8 vf = *(const u16x8*)(lVc + (nb * 16 + lr) * 32 + lg * 8);
        oacc[nb] = mfma16(pa, vf, oacc[nb]);
      }

      __builtin_amdgcn_s_barrier();   // readers done before next issue overwrites
      cur ^= 1;
    }

    float inv[4];
#pragma unroll
    for (int r = 0; r < 4; r++) inv[r] = 1.f / lse[r];
#pragma unroll
    for (int nb = 0; nb < 8; nb++)
#pragma unroll
      for (int r = 0; r < 4; r++) osum[nb][r] += oacc[nb][r] * inv[r];
  }

#pragma unroll
  for (int nb = 0; nb < 8; nb++)
#pragma unroll
    for (int r = 0; r < 4; r++)
      out[(long)(q0 + w * 16 + lg * 4 + r) * 1536 + h * 128 + nb * 16 + lr] =
          f2bf(osum[nb][r]);
}

// ---------- launcher ----------
extern "C" void kernel_launch(void* const* d_in, const int* in_sizes, int n_in,
                              void* d_out, int out_size, void* d_ws, size_t ws_size,
                              hipStream_t stream) {
  (void)in_sizes; (void)n_in; (void)out_size; (void)ws_size;
  const float* x    = (const float*)d_in[0];
  const float* ctx  = (const float*)d_in[1];
  const float* aud  = (const float*)d_in[2];
  const float* Wq   = (const float*)d_in[3];
  const float* bq   = (const float*)d_in[4];
  const float* Wk   = (const float*)d_in[5];
  const float* bk   = (const float*)d_in[6];
  const float* Wv   = (const float*)d_in[7];
  const float* bv   = (const float*)d_in[8];
  const float* Wki  = (const float*)d_in[9];
  const float* bki  = (const float*)d_in[10];
  const float* Wvi  = (const float*)d_in[11];
  const float* bvi  = (const float*)d_in[12];
  const float* Wo   = (const float*)d_in[13];
  const float* bo   = (const float*)d_in[14];
  const float* nqw  = (const float*)d_in[15];
  const float* nkw  = (const float*)d_in[16];
  const float* nkiw = (const float*)d_in[17];
  const float* Wkp  = (const float*)d_in[18];
  const float* Wvp  = (const float*)d_in[19];
  const int* clen   = (const int*)d_in[20];
  const int* alens  = (const int*)d_in[21];
  float* out = (float*)d_out;

  char* ws = (char*)d_ws;
  size_t o = 0;
  auto alloc = [&](size_t bytes) { char* p = ws + o; o += bytes; return p; };
  unsigned short* x_bf    = (unsigned short*)alloc(33030144);  // 10752x1536
  unsigned short* ctx_bf  = (unsigned short*)alloc(2362368);   // 769x1536
  unsigned short* aud_bf  = (unsigned short*)alloc(1032192);   // 672x768
  unsigned short* Wq_bf   = (unsigned short*)alloc(4718592);
  unsigned short* Wo_bf   = (unsigned short*)alloc(4718592);
  unsigned short* Wkv_bf  = (unsigned short*)alloc(9437184);   // [Wk;Wv] 3072x1536
  unsigned short* Wkvi_bf = (unsigned short*)alloc(9437184);   // [Wki;Wvi]
  unsigned short* Wkva_bf = (unsigned short*)alloc(4718592);   // [Wkp;Wvp] 3072x768
  float* q_f32   = (float*)alloc(66060288);                    // 10752x1536 f32
  float* kvt_f32 = (float*)alloc(3145728);                     // 512x1536 (K half)
  float* kvi_f32 = (float*)alloc(1579008);                     // 257x1536 (K half)
  unsigned short* q_bf  = (unsigned short*)alloc(33030144);
  unsigned short* kt_bf = (unsigned short*)alloc(1572864);     // 512x1536
  unsigned short* ki_bf = (unsigned short*)alloc(884736);      // 288x1536 (padded)
  unsigned short* ka_bf = (unsigned short*)alloc(2064384);     // 672x1536
  unsigned short* vtT   = (unsigned short*)alloc(1572864);     // [12][128][512]
  unsigned short* viT   = (unsigned short*)alloc(884736);      // [12][128][288] (pad)
  unsigned short* vaT   = (unsigned short*)alloc(2064384);     // [21][12][128][32]
  unsigned short* attn_bf = x_bf;   // x_bf dead after Q GEMM

  // one batched convert launch for all 11 tensors
  CJobs cj;
  cj.s[0] = x;    cj.d[0] = x_bf;                       cj.n4[0] = 10752 * 1536 / 4;
  cj.s[1] = ctx;  cj.d[1] = ctx_bf;                     cj.n4[1] = 769 * 1536 / 4;
  cj.s[2] = aud;  cj.d[2] = aud_bf;                     cj.n4[2] = 672 * 768 / 4;
  cj.s[3] = Wq;   cj.d[3] = Wq_bf;                      cj.n4[3] = 1536 * 1536 / 4;
  cj.s[4] = Wo;   cj.d[4] = Wo_bf;                      cj.n4[4] = 1536 * 1536 / 4;
  cj.s[5] = Wk;   cj.d[5] = Wkv_bf;                     cj.n4[5] = 1536 * 1536 / 4;
  cj.s[6] = Wv;   cj.d[6] = Wkv_bf + 1536 * 1536;       cj.n4[6] = 1536 * 1536 / 4;
  cj.s[7] = Wki;  cj.d[7] = Wkvi_bf;                    cj.n4[7] = 1536 * 1536 / 4;
  cj.s[8] = Wvi;  cj.d[8] = Wkvi_bf + 1536 * 1536;      cj.n4[8] = 1536 * 1536 / 4;
  cj.s[9] = Wkp;  cj.d[9] = Wkva_bf;                    cj.n4[9] = 1536 * 768 / 4;
  cj.s[10] = Wvp; cj.d[10] = Wkva_bf + 1536 * 768;      cj.n4[10] = 1536 * 768 / 4;
  k_convN<<<dim3(1024, 11), 256, 0, stream>>>(cj);

  // projections (KV GEMMs scatter V^T + audio-K directly as bf16)
  k_gemm<<<dim3(12, 84), 256, 0, stream>>>(x_bf, Wq_bf, q_f32, nullptr, nullptr, 0,
                                           10752, 1536, 1536, bq, nullptr);
  k_gemm<<<dim3(24, 4), 256, 0, stream>>>(ctx_bf + 257 * 1536, Wkv_bf, kvt_f32, nullptr,
                                          vtT, 512, 512, 3072, 1536, bk, bv);
  k_gemm<<<dim3(24, 3), 256, 0, stream>>>(ctx_bf, Wkvi_bf, kvi_f32, nullptr,
                                          viT, 288, 257, 3072, 1536, bki, bvi);
  k_gemm<<<dim3(24, 6), 256, 0, stream>>>(aud_bf, Wkva_bf, nullptr, ka_bf,
                                          vaT, 32, 672, 3072, 768, nullptr, nullptr);

  // RMSNorm + bf16 (Q gets 1/sqrt(128) folded in)
  k_postproc<<<10752, 256, 0, stream>>>(q_f32, nqw, q_bf, 0.08838834764831845f);
  k_postproc<<<512, 256, 0, stream>>>(kvt_f32, nkw, kt_bf, 1.0f);
  k_postproc<<<257, 256, 0, stream>>>(kvi_f32, nkiw, ki_bf, 1.0f);

  // fused img+txt+audio attention -> bf16
  k_attn<<<dim3(168, 12), 256, 0, stream>>>(q_bf, kt_bf, vtT, ki_bf, viT, ka_bf, vaT,
                                            clen, alens, attn_bf);

  // output projection
  k_gemm<<<dim3(12, 84), 256, 0, stream>>>(attn_bf, Wo_bf, out, nullptr, nullptr, 0,
                                           10752, 1536, 1536, bo, nullptr);
}

// Round 6
// 623.855 us; speedup vs baseline: 1.2549x; 1.1477x over previous
//
#include <hip/hip_runtime.h>

// ---------- types ----------
typedef __bf16 bf16x8 __attribute__((ext_vector_type(8)));
typedef unsigned short u16x8 __attribute__((ext_vector_type(8)));
typedef float f32x4 __attribute__((ext_vector_type(4)));

__device__ __forceinline__ unsigned short f2bf(float f) {
  __bf16 b = (__bf16)f;                     // native RNE cvt
  return __builtin_bit_cast(unsigned short, b);
}

__device__ __forceinline__ f32x4 mfma16(u16x8 a, u16x8 b, f32x4 c) {
  return __builtin_amdgcn_mfma_f32_16x16x32_bf16(
      __builtin_bit_cast(bf16x8, a), __builtin_bit_cast(bf16x8, b), c, 0, 0, 0);
}

// async global->LDS, 16B per lane; LDS dest is wave-uniform base + lane*16
#define GLD16(gp, lp)                                                              \
  __builtin_amdgcn_global_load_lds((const __attribute__((address_space(1))) void*)(gp), \
                                   (__attribute__((address_space(3))) void*)(lp), 16, 0, 0)

// ---------- batched f32 -> bf16 convert (one launch for all tensors) ----------
struct CJobs {
  const float* s[11];
  unsigned short* d[11];
  int n4[11];
};
__global__ __launch_bounds__(256) void k_convN(CJobs j) {
  const int job = blockIdx.y;
  const int n4 = j.n4[job];
  const float* __restrict__ src = j.s[job];
  unsigned short* __restrict__ dst = j.d[job];
  for (int i = blockIdx.x * 256 + threadIdx.x; i < n4; i += gridDim.x * 256) {
    float4 v = ((const float4*)src)[i];
    ushort4 o;
    o.x = f2bf(v.x); o.y = f2bf(v.y); o.z = f2bf(v.z); o.w = f2bf(v.w);
    ((ushort4*)dst)[i] = o;
  }
}

// ---------- big GEMM: C[M,1536] f32 = A[M,K]bf16 * B[1536,K]^T bf16 + bias ----------
// 256x256 tile, BK=64, 8 waves (2Mx4N), 128 KiB dbuf LDS, counted vmcnt(8) pipeline.
// LDS XOR-swizzle: slot (row, c) holds global chunk c ^ (row&7)  (16B chunks, 8/row).
__global__ __launch_bounds__(512, 2) void k_gemm256(const unsigned short* __restrict__ A,
                                                    const unsigned short* __restrict__ B,
                                                    float* __restrict__ C,
                                                    int M, int N, int K,
                                                    const float* __restrict__ bias) {
  __shared__ unsigned short lA[2][256 * 64];   // 32 KB each buf
  __shared__ unsigned short lB[2][256 * 64];
  const int tid = threadIdx.x;
  const int l = tid & 63, w = tid >> 6;
  const int wm = w >> 2, wn = w & 3;           // 2 x 4 waves
  const int lr = l & 15, lg = l >> 4;
  const int m0 = blockIdx.y * 256, n0 = blockIdx.x * 256;

  // staging: issue i covers rows [i*64, i*64+64); thread -> row i*64 + (tid>>3),
  // LDS chunk tid&7, global chunk pre-swizzled: (tid&7) ^ ((tid>>3)&7).
  const int srow = tid >> 3;
  const int g8 = ((tid & 7) ^ (srow & 7)) * 8;
  const unsigned short* pA = A + (long)(m0 + srow) * K + g8;
  const unsigned short* pB = B + (long)(n0 + srow) * K + g8;
  const long iStrA = (long)64 * K;

  // compute-side swizzled read offsets: row&7 == lr&7 for all frag rows
  const int rdA = (wm * 128 + lr) * 64;
  const int rdB = (wn * 64 + lr) * 64;
  const int ck[2] = { (lg ^ (lr & 7)) * 8, ((4 + lg) ^ (lr & 7)) * 8 };

  const f32x4 zero4 = {0.f, 0.f, 0.f, 0.f};
  f32x4 acc[8][4];
#pragma unroll
  for (int i = 0; i < 8; i++)
#pragma unroll
    for (int j = 0; j < 4; j++) acc[i][j] = zero4;

  const int NT = K >> 6;

  // prologue: stage tile 0 -> buf 0
#pragma unroll
  for (int i = 0; i < 4; i++) GLD16(pA + i * iStrA, &lA[0][(i * 512 + w * 64) * 8]);
#pragma unroll
  for (int i = 0; i < 4; i++) GLD16(pB + i * iStrA, &lB[0][(i * 512 + w * 64) * 8]);
  pA += 64; pB += 64;

  int cur = 0;
  for (int t = 0; t < NT; t++) {
    if (t + 1 < NT) {
      const int b = cur ^ 1;
#pragma unroll
      for (int i = 0; i < 4; i++) GLD16(pA + i * iStrA, &lA[b][(i * 512 + w * 64) * 8]);
#pragma unroll
      for (int i = 0; i < 4; i++) GLD16(pB + i * iStrA, &lB[b][(i * 512 + w * 64) * 8]);
      pA += 64; pB += 64;
      __builtin_amdgcn_sched_barrier(0);
      asm volatile("s_waitcnt vmcnt(8)" ::: "memory");   // tile t resident; t+1 in flight
    } else {
      __builtin_amdgcn_sched_barrier(0);
      asm volatile("s_waitcnt vmcnt(0)" ::: "memory");
    }
    __builtin_amdgcn_sched_barrier(0);
    __builtin_amdgcn_s_barrier();

    const unsigned short* lAc = lA[cur];
    const unsigned short* lBc = lB[cur];
#pragma unroll
    for (int ks = 0; ks < 2; ks++) {
      u16x8 a8[8], b4[4];
#pragma unroll
      for (int mb = 0; mb < 8; mb++)
        a8[mb] = *(const u16x8*)(lAc + rdA + mb * 16 * 64 + ck[ks]);
#pragma unroll
      for (int nb = 0; nb < 4; nb++)
        b4[nb] = *(const u16x8*)(lBc + rdB + nb * 16 * 64 + ck[ks]);
#pragma unroll
      for (int mb = 0; mb < 8; mb++)
#pragma unroll
        for (int nb = 0; nb < 4; nb++) acc[mb][nb] = mfma16(a8[mb], b4[nb], acc[mb][nb]);
    }
    __builtin_amdgcn_sched_barrier(0);
    __builtin_amdgcn_s_barrier();
    cur ^= 1;
  }

#pragma unroll
  for (int mb = 0; mb < 8; mb++)
#pragma unroll
    for (int nb = 0; nb < 4; nb++) {
      const int col = n0 + wn * 64 + nb * 16 + lr;
      const float bv = bias[col];
#pragma unroll
      for (int r = 0; r < 4; r++) {
        const int row = m0 + wm * 128 + mb * 16 + lg * 4 + r;
        C[(long)row * N + col] = acc[mb][nb][r] + bv;
      }
    }
}

// ---------- small GEMM: C[M,N] = A[M,K]bf16 * B[N,K]^T bf16 + bias ----------
// 128x128 tile, BK=32, 4 waves (2x2). m97 structure (global_load_lds staging).
__global__ __launch_bounds__(256) void k_gemm(const unsigned short* __restrict__ A,
                                              const unsigned short* __restrict__ B,
                                              float* __restrict__ Cf,
                                              unsigned short* __restrict__ CKbf,
                                              unsigned short* __restrict__ CVT, int NK,
                                              int M, int N, int K,
                                              const float* __restrict__ bias0,
                                              const float* __restrict__ bias1) {
  __shared__ unsigned short lA[128 * 32];  // linear row-major [128][32]
  __shared__ unsigned short lB[128 * 32];
  const int tid = threadIdx.x;
  const int l = tid & 63, w = tid >> 6;
  const int wm = w >> 1, wn = w & 1;
  const int lr = l & 15, lg = l >> 4;
  const int m0 = blockIdx.y * 128, n0 = blockIdx.x * 128;

  const int srow = w * 16 + (l >> 2);
  const int sk8 = (l & 3) * 8;
  int raA0 = m0 + srow;       if (raA0 >= M) raA0 = M - 1;
  int raA1 = m0 + 64 + srow;  if (raA1 >= M) raA1 = M - 1;
  const long rbB0 = (long)(n0 + srow) * K;
  const long rbB1 = (long)(n0 + 64 + srow) * K;
  const long raA0o = (long)raA0 * K, raA1o = (long)raA1 * K;
  unsigned short* ldsA0 = &lA[(w * 16) * 32];
  unsigned short* ldsA1 = &lA[(64 + w * 16) * 32];
  unsigned short* ldsB0 = &lB[(w * 16) * 32];
  unsigned short* ldsB1 = &lB[(64 + w * 16) * 32];

  const f32x4 zero4 = {0.f, 0.f, 0.f, 0.f};
  f32x4 acc[4][4];
#pragma unroll
  for (int i = 0; i < 4; i++)
#pragma unroll
    for (int j = 0; j < 4; j++) acc[i][j] = zero4;

  for (int k0 = 0; k0 < K; k0 += 32) {
    __syncthreads();
    GLD16(A + raA0o + k0 + sk8, ldsA0);
    GLD16(A + raA1o + k0 + sk8, ldsA1);
    GLD16(B + rbB0 + k0 + sk8, ldsB0);
    GLD16(B + rbB1 + k0 + sk8, ldsB1);
    __syncthreads();

    u16x8 af[4], bfr[4];
#pragma unroll
    for (int mb = 0; mb < 4; mb++)
      af[mb] = *(const u16x8*)(&lA[(wm * 64 + mb * 16 + lr) * 32 + lg * 8]);
#pragma unroll
    for (int nb = 0; nb < 4; nb++)
      bfr[nb] = *(const u16x8*)(&lB[(wn * 64 + nb * 16 + lr) * 32 + lg * 8]);
#pragma unroll
    for (int mb = 0; mb < 4; mb++)
#pragma unroll
      for (int nb = 0; nb < 4; nb++) acc[mb][nb] = mfma16(af[mb], bfr[nb], acc[mb][nb]);
  }

#pragma unroll
  for (int mb = 0; mb < 4; mb++)
#pragma unroll
    for (int nb = 0; nb < 4; nb++)
#pragma unroll
      for (int r = 0; r < 4; r++) {
        int row = m0 + wm * 64 + mb * 16 + lg * 4 + r;
        if (row < M) {
          int col = n0 + wn * 64 + nb * 16 + lr;
          float b = 0.f;
          if (col < 1536) { if (bias0) b = bias0[col]; }
          else            { if (bias1) b = bias1[col - 1536]; }
          float val = acc[mb][nb][r] + b;
          if (col < 1536) {
            if (CKbf) CKbf[(long)row * 1536 + col] = f2bf(val);
            else      Cf[(long)row * 1536 + col] = val;
          } else {
            int c2 = col - 1536, hh = c2 >> 7, dd = c2 & 127;
            long addr = (NK == 32)
                ? ((((long)(row >> 5) * 12 + hh) * 128 + dd) * 32 + (row & 31))
                : (((long)hh * 128 + dd) * NK + row);
            CVT[addr] = f2bf(val);
          }
        }
      }
}

// ---------- per-row RMSNorm over 1536 cols, f32->bf16 (w scaled by pscale) ----------
__global__ __launch_bounds__(256) void k_postproc(const float* __restrict__ src,
                                                  const float* __restrict__ w,
                                                  unsigned short* __restrict__ dst,
                                                  float pscale) {
  const int row = blockIdx.x;
  const float* s = src + (long)row * 1536;
  float v[6];
  float ss = 0.f;
#pragma unroll
  for (int i = 0; i < 6; i++) {
    v[i] = s[threadIdx.x + i * 256];
    ss += v[i] * v[i];
  }
#pragma unroll
  for (int o = 1; o < 64; o <<= 1) ss += __shfl_xor(ss, o, 64);
  __shared__ float red[4];
  if ((threadIdx.x & 63) == 0) red[threadIdx.x >> 6] = ss;
  __syncthreads();
  float tot = red[0] + red[1] + red[2] + red[3];
  float scale = rsqrtf(tot * (1.f / 1536.f) + 1e-6f) * pscale;
  unsigned short* d = dst + (long)row * 1536;
#pragma unroll
  for (int i = 0; i < 6; i++)
    d[threadIdx.x + i * 256] = f2bf(v[i] * scale * w[threadIdx.x + i * 256]);
}

// ---------- fused 3-way flash attention ----------
// grid (168 q-tiles of 64, 12 heads), 4 waves x 16 q-rows.
// Q pre-scaled by 1/sqrt(128). Pointer-increment dbuf staging, counted vmcnt.
__global__ __launch_bounds__(256) void k_attn(
    const unsigned short* __restrict__ qb, const unsigned short* __restrict__ kt,
    const unsigned short* __restrict__ vtT, const unsigned short* __restrict__ ki,
    const unsigned short* __restrict__ viT, const unsigned short* __restrict__ ka,
    const unsigned short* __restrict__ vaT, const int* __restrict__ clen_p,
    const int* __restrict__ alens, unsigned short* __restrict__ out) {
  __shared__ unsigned short lK[2][32 * 128];   // 8KB per buffer
  __shared__ unsigned short lV[2][128 * 32];   // 8KB per buffer
  __shared__ unsigned short lP[4][16 * 40];    // per-wave P transpose

  const int qt = blockIdx.x, h = blockIdx.y;
  const int tid = threadIdx.x, l = tid & 63, w = tid >> 6;
  const int lr = l & 15, lg = l >> 4;
  const int q0 = qt * 64;
  const int frame = qt >> 3;

  // staging lane constants
  const int key0 = tid >> 4;                    // 0..15 (i=1 adds 16)
  const int swc8 = ((tid & 15) ^ (key0 & 7)) * 8;  // pre-swizzled K chunk
  const int d0 = tid >> 2;                      // 0..63 (i=1 adds 64)
  const int kc8 = (tid & 3) * 8;

  u16x8 qf[4];
  {
    const unsigned short* qp = qb + (long)(q0 + w * 16 + lr) * 1536 + h * 128;
#pragma unroll
    for (int kk = 0; kk < 4; kk++) qf[kk] = *(const u16x8*)(qp + kk * 32 + lg * 8);
  }

  const f32x4 zero4 = {0.f, 0.f, 0.f, 0.f};
  f32x4 osum[8];
#pragma unroll
  for (int nb = 0; nb < 8; nb++) osum[nb] = zero4;

  for (int ph = 0; ph < 3; ph++) {
    const unsigned short *kp, *vtp;
    int klen, NK;
    if (ph == 0) {
      kp = ki; vtp = viT + (long)h * 128 * 288; klen = 257; NK = 288;
    } else if (ph == 1) {
      kp = kt; vtp = vtT + (long)h * 128 * 512; klen = clen_p[0]; NK = 512;
    } else {
      kp = ka + (long)frame * 32 * 1536;
      vtp = vaT + (long)frame * 49152 + h * 4096;
      klen = alens[frame]; NK = 32;
    }

    // running staging pointers (advance by one 32-key tile each stage)
    const unsigned short* pk0 = kp + (long)key0 * 1536 + h * 128 + swc8;
    const unsigned short* pk1 = pk0 + 16 * 1536;
    const unsigned short* pv0 = vtp + (long)d0 * NK + kc8;
    const unsigned short* pv1 = pv0 + (long)64 * NK;

    float m[4], lse[4];
#pragma unroll
    for (int r = 0; r < 4; r++) { m[r] = -1e30f; lse[r] = 0.f; }
    f32x4 oacc[8];
#pragma unroll
    for (int nb = 0; nb < 8; nb++) oacc[nb] = zero4;

    const int nt = (klen + 31) >> 5;

    // stage tile 0 into buffer 0
    GLD16(pk0, &lK[0][(w * 64) * 8]);
    GLD16(pk1, &lK[0][(256 + w * 64) * 8]);
    GLD16(pv0, &lV[0][(w * 64) * 8]);
    GLD16(pv1, &lV[0][(256 + w * 64) * 8]);
    pk0 += 32 * 1536; pk1 += 32 * 1536; pv0 += 32; pv1 += 32;

    int cur = 0;
    for (int t = 0; t < nt; t++) {
      const int kb0 = t * 32;
      if (t + 1 < nt) {
        const int b = cur ^ 1;
        GLD16(pk0, &lK[b][(w * 64) * 8]);
        GLD16(pk1, &lK[b][(256 + w * 64) * 8]);
        GLD16(pv0, &lV[b][(w * 64) * 8]);
        GLD16(pv1, &lV[b][(256 + w * 64) * 8]);
        pk0 += 32 * 1536; pk1 += 32 * 1536; pv0 += 32; pv1 += 32;
        __builtin_amdgcn_sched_barrier(0);
        asm volatile("s_waitcnt vmcnt(4)" ::: "memory");
      } else {
        __builtin_amdgcn_sched_barrier(0);
        asm volatile("s_waitcnt vmcnt(0)" ::: "memory");
      }
      __builtin_amdgcn_sched_barrier(0);
      __builtin_amdgcn_s_barrier();   // current tile visible to all waves

      const unsigned short* lKc = &lK[cur][0];
      const unsigned short* lVc = &lV[cur][0];

      // S = Q(16x128) * K^T(128x32), swizzled K reads (conflict-free)
      f32x4 s0 = zero4, s1 = zero4;
      __builtin_amdgcn_s_setprio(1);
#pragma unroll
      for (int kk = 0; kk < 4; kk++) {
        int c = (kk * 4 + lg) ^ (lr & 7);
        u16x8 k0f = *(const u16x8*)(lKc + lr * 128 + c * 8);
        u16x8 k1f = *(const u16x8*)(lKc + (16 + lr) * 128 + c * 8);
        s0 = mfma16(qf[kk], k0f, s0);
        s1 = mfma16(qf[kk], k1f, s1);
      }
      __builtin_amdgcn_s_setprio(0);

      float p0[4], p1[4], pm[4];
      if (kb0 + 32 <= klen) {            // interior tile: no masking
#pragma unroll
        for (int r = 0; r < 4; r++) {
          p0[r] = s0[r]; p1[r] = s1[r];
          pm[r] = fmaxf(p0[r], p1[r]);
        }
      } else {                            // boundary tile
        const bool v0 = (kb0 + lr) < klen;
        const bool v1 = (kb0 + 16 + lr) < klen;
#pragma unroll
        for (int r = 0; r < 4; r++) {
          p0[r] = v0 ? s0[r] : -1e30f;
          p1[r] = v1 ? s1[r] : -1e30f;
          pm[r] = fmaxf(p0[r], p1[r]);
        }
      }
#pragma unroll
      for (int o = 1; o < 16; o <<= 1) {
#pragma unroll
        for (int r = 0; r < 4; r++) pm[r] = fmaxf(pm[r], __shfl_xor(pm[r], o, 64));
      }
      // T13 defer-max: only rescale when max grew by > 8
      bool grow = (pm[0] > m[0] + 8.f) || (pm[1] > m[1] + 8.f) ||
                  (pm[2] > m[2] + 8.f) || (pm[3] > m[3] + 8.f);
      if (__any(grow)) {
#pragma unroll
        for (int r = 0; r < 4; r++) {
          float mn = fmaxf(m[r], pm[r]);
          float alpha = __expf(m[r] - mn);
          m[r] = mn;
          lse[r] *= alpha;
#pragma unroll
          for (int nb = 0; nb < 8; nb++) oacc[nb][r] *= alpha;
        }
      }
      float rs[4];
#pragma unroll
      for (int r = 0; r < 4; r++) {
        p0[r] = __expf(p0[r] - m[r]);
        p1[r] = __expf(p1[r] - m[r]);
        rs[r] = p0[r] + p1[r];
      }
#pragma unroll
      for (int o = 1; o < 16; o <<= 1) {
#pragma unroll
        for (int r = 0; r < 4; r++) rs[r] += __shfl_xor(rs[r], o, 64);
      }
#pragma unroll
      for (int r = 0; r < 4; r++) lse[r] += rs[r];

      // P (C-layout) -> per-wave LDS -> A-layout frag
#pragma unroll
      for (int r = 0; r < 4; r++) {
        lP[w][(lg * 4 + r) * 40 + lr] = f2bf(p0[r]);
        lP[w][(lg * 4 + r) * 40 + 16 + lr] = f2bf(p1[r]);
      }
      u16x8 pa = *(const u16x8*)(&lP[w][lr * 40 + lg * 8]);
      __builtin_amdgcn_s_setprio(1);
#pragma unroll
      for (int nb = 0; nb < 8; nb++) {
        u16x8 vf = *(const u16x8*)(lVc + (nb * 16 + lr) * 32 + lg * 8);
        oacc[nb] = mfma16(pa, vf, oacc[nb]);
      }
      __builtin_amdgcn_s_setprio(0);

      __builtin_amdgcn_s_barrier();   // readers done before next issue overwrites
      cur ^= 1;
    }

    float inv[4];
#pragma unroll
    for (int r = 0; r < 4; r++) inv[r] = 1.f / lse[r];
#pragma unroll
    for (int nb = 0; nb < 8; nb++)
#pragma unroll
      for (int r = 0; r < 4; r++) osum[nb][r] += oacc[nb][r] * inv[r];
  }

#pragma unroll
  for (int nb = 0; nb < 8; nb++)
#pragma unroll
    for (int r = 0; r < 4; r++)
      out[(long)(q0 + w * 16 + lg * 4 + r) * 1536 + h * 128 + nb * 16 + lr] =
          f2bf(osum[nb][r]);
}

// ---------- launcher ----------
extern "C" void kernel_launch(void* const* d_in, const int* in_sizes, int n_in,
                              void* d_out, int out_size, void* d_ws, size_t ws_size,
                              hipStream_t stream) {
  (void)in_sizes; (void)n_in; (void)out_size; (void)ws_size;
  const float* x    = (const float*)d_in[0];
  const float* ctx  = (const float*)d_in[1];
  const float* aud  = (const float*)d_in[2];
  const float* Wq   = (const float*)d_in[3];
  const float* bq   = (const float*)d_in[4];
  const float* Wk   = (const float*)d_in[5];
  const float* bk   = (const float*)d_in[6];
  const float* Wv   = (const float*)d_in[7];
  const float* bv   = (const float*)d_in[8];
  const float* Wki  = (const float*)d_in[9];
  const float* bki  = (const float*)d_in[10];
  const float* Wvi  = (const float*)d_in[11];
  const float* bvi  = (const float*)d_in[12];
  const float* Wo   = (const float*)d_in[13];
  const float* bo   = (const float*)d_in[14];
  const float* nqw  = (const float*)d_in[15];
  const float* nkw  = (const float*)d_in[16];
  const float* nkiw = (const float*)d_in[17];
  const float* Wkp  = (const float*)d_in[18];
  const float* Wvp  = (const float*)d_in[19];
  const int* clen   = (const int*)d_in[20];
  const int* alens  = (const int*)d_in[21];
  float* out = (float*)d_out;

  char* ws = (char*)d_ws;
  size_t o = 0;
  auto alloc = [&](size_t bytes) { char* p = ws + o; o += bytes; return p; };
  unsigned short* x_bf    = (unsigned short*)alloc(33030144);  // 10752x1536
  unsigned short* ctx_bf  = (unsigned short*)alloc(2362368);   // 769x1536
  unsigned short* aud_bf  = (unsigned short*)alloc(1032192);   // 672x768
  unsigned short* Wq_bf   = (unsigned short*)alloc(4718592);
  unsigned short* Wo_bf   = (unsigned short*)alloc(4718592);
  unsigned short* Wkv_bf  = (unsigned short*)alloc(9437184);   // [Wk;Wv] 3072x1536
  unsigned short* Wkvi_bf = (unsigned short*)alloc(9437184);   // [Wki;Wvi]
  unsigned short* Wkva_bf = (unsigned short*)alloc(4718592);   // [Wkp;Wvp] 3072x768
  float* q_f32   = (float*)alloc(66060288);                    // 10752x1536 f32
  float* kvt_f32 = (float*)alloc(3145728);                     // 512x1536 (K half)
  float* kvi_f32 = (float*)alloc(1579008);                     // 257x1536 (K half)
  unsigned short* q_bf  = (unsigned short*)alloc(33030144);
  unsigned short* kt_bf = (unsigned short*)alloc(1572864);     // 512x1536
  unsigned short* ki_bf = (unsigned short*)alloc(884736);      // 288x1536 (padded)
  unsigned short* ka_bf = (unsigned short*)alloc(2064384);     // 672x1536
  unsigned short* vtT   = (unsigned short*)alloc(1572864);     // [12][128][512]
  unsigned short* viT   = (unsigned short*)alloc(884736);      // [12][128][288] (pad)
  unsigned short* vaT   = (unsigned short*)alloc(2064384);     // [21][12][128][32]
  unsigned short* attn_bf = x_bf;   // x_bf dead after Q GEMM

  // one batched convert launch for all 11 tensors
  CJobs cj;
  cj.s[0] = x;    cj.d[0] = x_bf;                       cj.n4[0] = 10752 * 1536 / 4;
  cj.s[1] = ctx;  cj.d[1] = ctx_bf;                     cj.n4[1] = 769 * 1536 / 4;
  cj.s[2] = aud;  cj.d[2] = aud_bf;                     cj.n4[2] = 672 * 768 / 4;
  cj.s[3] = Wq;   cj.d[3] = Wq_bf;                      cj.n4[3] = 1536 * 1536 / 4;
  cj.s[4] = Wo;   cj.d[4] = Wo_bf;                      cj.n4[4] = 1536 * 1536 / 4;
  cj.s[5] = Wk;   cj.d[5] = Wkv_bf;                     cj.n4[5] = 1536 * 1536 / 4;
  cj.s[6] = Wv;   cj.d[6] = Wkv_bf + 1536 * 1536;       cj.n4[6] = 1536 * 1536 / 4;
  cj.s[7] = Wki;  cj.d[7] = Wkvi_bf;                    cj.n4[7] = 1536 * 1536 / 4;
  cj.s[8] = Wvi;  cj.d[8] = Wkvi_bf + 1536 * 1536;      cj.n4[8] = 1536 * 1536 / 4;
  cj.s[9] = Wkp;  cj.d[9] = Wkva_bf;                    cj.n4[9] = 1536 * 768 / 4;
  cj.s[10] = Wvp; cj.d[10] = Wkva_bf + 1536 * 768;      cj.n4[10] = 1536 * 768 / 4;
  k_convN<<<dim3(1024, 11), 256, 0, stream>>>(cj);

  // big projections: 256^2 counted-vmcnt pipeline
  k_gemm256<<<dim3(6, 42), 512, 0, stream>>>(x_bf, Wq_bf, q_f32, 10752, 1536, 1536, bq);

  // small projections (KV GEMMs scatter V^T + audio-K directly as bf16)
  k_gemm<<<dim3(24, 4), 256, 0, stream>>>(ctx_bf + 257 * 1536, Wkv_bf, kvt_f32, nullptr,
                                          vtT, 512, 512, 3072, 1536, bk, bv);
  k_gemm<<<dim3(24, 3), 256, 0, stream>>>(ctx_bf, Wkvi_bf, kvi_f32, nullptr,
                                          viT, 288, 257, 3072, 1536, bki, bvi);
  k_gemm<<<dim3(24, 6), 256, 0, stream>>>(aud_bf, Wkva_bf, nullptr, ka_bf,
                                          vaT, 32, 672, 3072, 768, nullptr, nullptr);

  // RMSNorm + bf16 (Q gets 1/sqrt(128) folded in)
  k_postproc<<<10752, 256, 0, stream>>>(q_f32, nqw, q_bf, 0.08838834764831845f);
  k_postproc<<<512, 256, 0, stream>>>(kvt_f32, nkw, kt_bf, 1.0f);
  k_postproc<<<257, 256, 0, stream>>>(kvi_f32, nkiw, ki_bf, 1.0f);

  // fused img+txt+audio attention -> bf16
  k_attn<<<dim3(168, 12), 256, 0, stream>>>(q_bf, kt_bf, vtT, ki_bf, viT, ka_bf, vaT,
                                            clen, alens, attn_bf);

  // output projection
  k_gemm256<<<dim3(6, 42), 512, 0, stream>>>(attn_bf, Wo_bf, out, 10752, 1536, 1536, bo);
}

// Round 7
// 492.841 us; speedup vs baseline: 1.5885x; 1.2658x over previous
//
#include <hip/hip_runtime.h>

// ---------- types ----------
typedef __bf16 bf16x8 __attribute__((ext_vector_type(8)));
typedef unsigned short u16x8 __attribute__((ext_vector_type(8)));
typedef float f32x4 __attribute__((ext_vector_type(4)));

__device__ __forceinline__ unsigned short f2bf(float f) {
  __bf16 b = (__bf16)f;                     // native RNE cvt
  return __builtin_bit_cast(unsigned short, b);
}

__device__ __forceinline__ f32x4 mfma16(u16x8 a, u16x8 b, f32x4 c) {
  return __builtin_amdgcn_mfma_f32_16x16x32_bf16(
      __builtin_bit_cast(bf16x8, a), __builtin_bit_cast(bf16x8, b), c, 0, 0, 0);
}

// async global->LDS, 16B per lane; LDS dest is wave-uniform base + lane*16
#define GLD16(gp, lp)                                                              \
  __builtin_amdgcn_global_load_lds((const __attribute__((address_space(1))) void*)(gp), \
                                   (__attribute__((address_space(3))) void*)(lp), 16, 0, 0)

// ---------- batched f32 -> bf16 convert (one launch for all tensors) ----------
struct CJobs {
  const float* s[11];
  unsigned short* d[11];
  int n4[11];
};
__global__ __launch_bounds__(256) void k_convN(CJobs j) {
  const int job = blockIdx.y;
  const int n4 = j.n4[job];
  const float* __restrict__ src = j.s[job];
  unsigned short* __restrict__ dst = j.d[job];
  for (int i = blockIdx.x * 256 + threadIdx.x; i < n4; i += gridDim.x * 256) {
    float4 v = ((const float4*)src)[i];
    ushort4 o;
    o.x = f2bf(v.x); o.y = f2bf(v.y); o.z = f2bf(v.z); o.w = f2bf(v.w);
    ((ushort4*)dst)[i] = o;
  }
}

// ---------- big GEMM: C[M,1536] f32 = A[M,K]bf16 * B[1536,K]^T bf16 + bias ----------
// 256x256 tile, BK=64, 8 waves (2Mx4N), 128 KiB dbuf LDS, counted vmcnt(8) pipeline.
__global__ __launch_bounds__(512, 2) void k_gemm256(const unsigned short* __restrict__ A,
                                                    const unsigned short* __restrict__ B,
                                                    float* __restrict__ C,
                                                    int M, int N, int K,
                                                    const float* __restrict__ bias) {
  __shared__ unsigned short lA[2][256 * 64];   // 32 KB each buf
  __shared__ unsigned short lB[2][256 * 64];
  const int tid = threadIdx.x;
  const int l = tid & 63, w = tid >> 6;
  const int wm = w >> 2, wn = w & 3;           // 2 x 4 waves
  const int lr = l & 15, lg = l >> 4;
  const int m0 = blockIdx.y * 256, n0 = blockIdx.x * 256;

  const int srow = tid >> 3;
  const int g8 = ((tid & 7) ^ (srow & 7)) * 8;
  const unsigned short* pA = A + (long)(m0 + srow) * K + g8;
  const unsigned short* pB = B + (long)(n0 + srow) * K + g8;
  const long iStrA = (long)64 * K;

  const int rdA = (wm * 128 + lr) * 64;
  const int rdB = (wn * 64 + lr) * 64;
  const int ck[2] = { (lg ^ (lr & 7)) * 8, ((4 + lg) ^ (lr & 7)) * 8 };

  const f32x4 zero4 = {0.f, 0.f, 0.f, 0.f};
  f32x4 acc[8][4];
#pragma unroll
  for (int i = 0; i < 8; i++)
#pragma unroll
    for (int j = 0; j < 4; j++) acc[i][j] = zero4;

  const int NT = K >> 6;

#pragma unroll
  for (int i = 0; i < 4; i++) GLD16(pA + i * iStrA, &lA[0][(i * 512 + w * 64) * 8]);
#pragma unroll
  for (int i = 0; i < 4; i++) GLD16(pB + i * iStrA, &lB[0][(i * 512 + w * 64) * 8]);
  pA += 64; pB += 64;

  int cur = 0;
  for (int t = 0; t < NT; t++) {
    if (t + 1 < NT) {
      const int b = cur ^ 1;
#pragma unroll
      for (int i = 0; i < 4; i++) GLD16(pA + i * iStrA, &lA[b][(i * 512 + w * 64) * 8]);
#pragma unroll
      for (int i = 0; i < 4; i++) GLD16(pB + i * iStrA, &lB[b][(i * 512 + w * 64) * 8]);
      pA += 64; pB += 64;
      __builtin_amdgcn_sched_barrier(0);
      asm volatile("s_waitcnt vmcnt(8)" ::: "memory");
    } else {
      __builtin_amdgcn_sched_barrier(0);
      asm volatile("s_waitcnt vmcnt(0)" ::: "memory");
    }
    __builtin_amdgcn_sched_barrier(0);
    __builtin_amdgcn_s_barrier();

    const unsigned short* lAc = lA[cur];
    const unsigned short* lBc = lB[cur];
#pragma unroll
    for (int ks = 0; ks < 2; ks++) {
      u16x8 a8[8], b4[4];
#pragma unroll
      for (int mb = 0; mb < 8; mb++)
        a8[mb] = *(const u16x8*)(lAc + rdA + mb * 16 * 64 + ck[ks]);
#pragma unroll
      for (int nb = 0; nb < 4; nb++)
        b4[nb] = *(const u16x8*)(lBc + rdB + nb * 16 * 64 + ck[ks]);
#pragma unroll
      for (int mb = 0; mb < 8; mb++)
#pragma unroll
        for (int nb = 0; nb < 4; nb++) acc[mb][nb] = mfma16(a8[mb], b4[nb], acc[mb][nb]);
    }
    __builtin_amdgcn_sched_barrier(0);
    __builtin_amdgcn_s_barrier();
    cur ^= 1;
  }

#pragma unroll
  for (int mb = 0; mb < 8; mb++)
#pragma unroll
    for (int nb = 0; nb < 4; nb++) {
      const int col = n0 + wn * 64 + nb * 16 + lr;
      const float bv = bias[col];
#pragma unroll
      for (int r = 0; r < 4; r++) {
        const int row = m0 + wm * 128 + mb * 16 + lg * 4 + r;
        C[(long)row * N + col] = acc[mb][nb][r] + bv;
      }
    }
}

// ---------- merged small GEMMs: 3 jobs in one launch ----------
struct GJob {
  const unsigned short* A; const unsigned short* B;
  float* Cf; unsigned short* CKbf; unsigned short* CVT;
  int NK, M, K, nbx, bstart;
  const float* bias0; const float* bias1;
};
struct GJobs { GJob j[3]; };

__global__ __launch_bounds__(256) void k_gemm_small(GJobs js) {
  const int bid = blockIdx.x;
  const int ji = (bid >= js.j[1].bstart) + (bid >= js.j[2].bstart);
  const GJob J = js.j[ji];
  const int rel = bid - J.bstart;
  const int m0 = (rel / J.nbx) * 128, n0 = (rel % J.nbx) * 128;
  const int M = J.M, K = J.K;
  const int N = 3072;

  __shared__ unsigned short lA[128 * 32];
  __shared__ unsigned short lB[128 * 32];
  const int tid = threadIdx.x;
  const int l = tid & 63, w = tid >> 6;
  const int wm = w >> 1, wn = w & 1;
  const int lr = l & 15, lg = l >> 4;

  const int srow = w * 16 + (l >> 2);
  const int sk8 = (l & 3) * 8;
  int raA0 = m0 + srow;       if (raA0 >= M) raA0 = M - 1;
  int raA1 = m0 + 64 + srow;  if (raA1 >= M) raA1 = M - 1;
  const long rbB0 = (long)(n0 + srow) * K;
  const long rbB1 = (long)(n0 + 64 + srow) * K;
  const long raA0o = (long)raA0 * K, raA1o = (long)raA1 * K;
  unsigned short* ldsA0 = &lA[(w * 16) * 32];
  unsigned short* ldsA1 = &lA[(64 + w * 16) * 32];
  unsigned short* ldsB0 = &lB[(w * 16) * 32];
  unsigned short* ldsB1 = &lB[(64 + w * 16) * 32];

  const f32x4 zero4 = {0.f, 0.f, 0.f, 0.f};
  f32x4 acc[4][4];
#pragma unroll
  for (int i = 0; i < 4; i++)
#pragma unroll
    for (int j = 0; j < 4; j++) acc[i][j] = zero4;

  for (int k0 = 0; k0 < K; k0 += 32) {
    __syncthreads();
    GLD16(J.A + raA0o + k0 + sk8, ldsA0);
    GLD16(J.A + raA1o + k0 + sk8, ldsA1);
    GLD16(J.B + rbB0 + k0 + sk8, ldsB0);
    GLD16(J.B + rbB1 + k0 + sk8, ldsB1);
    __syncthreads();

    u16x8 af[4], bfr[4];
#pragma unroll
    for (int mb = 0; mb < 4; mb++)
      af[mb] = *(const u16x8*)(&lA[(wm * 64 + mb * 16 + lr) * 32 + lg * 8]);
#pragma unroll
    for (int nb = 0; nb < 4; nb++)
      bfr[nb] = *(const u16x8*)(&lB[(wn * 64 + nb * 16 + lr) * 32 + lg * 8]);
#pragma unroll
    for (int mb = 0; mb < 4; mb++)
#pragma unroll
      for (int nb = 0; nb < 4; nb++) acc[mb][nb] = mfma16(af[mb], bfr[nb], acc[mb][nb]);
  }

#pragma unroll
  for (int mb = 0; mb < 4; mb++)
#pragma unroll
    for (int nb = 0; nb < 4; nb++)
#pragma unroll
      for (int r = 0; r < 4; r++) {
        int row = m0 + wm * 64 + mb * 16 + lg * 4 + r;
        if (row < M) {
          int col = n0 + wn * 64 + nb * 16 + lr;
          float b = 0.f;
          if (col < 1536) { if (J.bias0) b = J.bias0[col]; }
          else            { if (J.bias1) b = J.bias1[col - 1536]; }
          float val = acc[mb][nb][r] + b;
          if (col < 1536) {
            if (J.CKbf) J.CKbf[(long)row * 1536 + col] = f2bf(val);
            else        J.Cf[(long)row * 1536 + col] = val;
          } else {
            int c2 = col - 1536, hh = c2 >> 7, dd = c2 & 127;
            long addr = (J.NK == 32)
                ? ((((long)(row >> 5) * 12 + hh) * 128 + dd) * 32 + (row & 31))
                : (((long)hh * 128 + dd) * J.NK + row);
            J.CVT[addr] = f2bf(val);
          }
        }
      }
}

// ---------- merged per-row RMSNorm (3 jobs), f32->bf16 ----------
struct PJob { const float* src; const float* w; unsigned short* dst; float pscale; int rstart; };
struct PJobs { PJob j[3]; };
__global__ __launch_bounds__(256) void k_postproc(PJobs js) {
  const int bid = blockIdx.x;
  const int ji = (bid >= js.j[1].rstart) + (bid >= js.j[2].rstart);
  const PJob J = js.j[ji];
  const int row = bid - J.rstart;
  const float* s = J.src + (long)row * 1536;
  float v[6];
  float ss = 0.f;
#pragma unroll
  for (int i = 0; i < 6; i++) {
    v[i] = s[threadIdx.x + i * 256];
    ss += v[i] * v[i];
  }
#pragma unroll
  for (int o = 1; o < 64; o <<= 1) ss += __shfl_xor(ss, o, 64);
  __shared__ float red[4];
  if ((threadIdx.x & 63) == 0) red[threadIdx.x >> 6] = ss;
  __syncthreads();
  float tot = red[0] + red[1] + red[2] + red[3];
  float scale = rsqrtf(tot * (1.f / 1536.f) + 1e-6f) * J.pscale;
  unsigned short* d = J.dst + (long)row * 1536;
#pragma unroll
  for (int i = 0; i < 6; i++)
    d[threadIdx.x + i * 256] = f2bf(v[i] * scale * J.w[threadIdx.x + i * 256]);
}

// ---------- fused 3-way flash attention (swapped QK^T, in-lane softmax) ----------
// grid (168 q-tiles of 64, 12 heads), 4 waves x 16 q-rows.
// S^T = mfma(K,Q): thread holds 8 keys of q-row q=lr -> row softmax is in-lane
// (7 fmax/adds) + 2 shuffles. Q pre-scaled by 1/sqrt(128).
__global__ __launch_bounds__(256) void k_attn(
    const unsigned short* __restrict__ qb, const unsigned short* __restrict__ kt,
    const unsigned short* __restrict__ vtT, const unsigned short* __restrict__ ki,
    const unsigned short* __restrict__ viT, const unsigned short* __restrict__ ka,
    const unsigned short* __restrict__ vaT, const int* __restrict__ clen_p,
    const int* __restrict__ alens, unsigned short* __restrict__ out) {
  __shared__ unsigned short lK[2][32 * 128];   // 8KB per buffer
  __shared__ unsigned short lV[2][128 * 32];   // 8KB per buffer
  __shared__ unsigned short lP[4][16 * 40];    // per-wave P transpose

  const int qt = blockIdx.x, h = blockIdx.y;
  const int tid = threadIdx.x, l = tid & 63, w = tid >> 6;
  const int lr = l & 15, lg = l >> 4;
  const int q0 = qt * 64;
  const int frame = qt >> 3;

  // staging lane constants
  const int key0 = tid >> 4;
  const int swc8 = ((tid & 15) ^ (key0 & 7)) * 8;
  const int d0 = tid >> 2;
  const int kc8 = (tid & 3) * 8;

  u16x8 qf[4];
  {
    const unsigned short* qp = qb + (long)(q0 + w * 16 + lr) * 1536 + h * 128;
#pragma unroll
    for (int kk = 0; kk < 4; kk++) qf[kk] = *(const u16x8*)(qp + kk * 32 + lg * 8);
  }

  const f32x4 zero4 = {0.f, 0.f, 0.f, 0.f};
  f32x4 osum[8];
#pragma unroll
  for (int nb = 0; nb < 8; nb++) osum[nb] = zero4;

  for (int ph = 0; ph < 3; ph++) {
    const unsigned short *kp, *vtp;
    int klen, NK;
    if (ph == 0) {
      kp = ki; vtp = viT + (long)h * 128 * 288; klen = 257; NK = 288;
    } else if (ph == 1) {
      kp = kt; vtp = vtT + (long)h * 128 * 512; klen = clen_p[0]; NK = 512;
    } else {
      kp = ka + (long)frame * 32 * 1536;
      vtp = vaT + (long)frame * 49152 + h * 4096;
      klen = alens[frame]; NK = 32;
    }

    const unsigned short* pk0 = kp + (long)key0 * 1536 + h * 128 + swc8;
    const unsigned short* pk1 = pk0 + 16 * 1536;
    const unsigned short* pv0 = vtp + (long)d0 * NK + kc8;
    const unsigned short* pv1 = pv0 + (long)64 * NK;

    float mloc = -1e30f, lseloc = 0.f;
    f32x4 oacc[8];
#pragma unroll
    for (int nb = 0; nb < 8; nb++) oacc[nb] = zero4;

    const int nt = (klen + 31) >> 5;

    GLD16(pk0, &lK[0][(w * 64) * 8]);
    GLD16(pk1, &lK[0][(256 + w * 64) * 8]);
    GLD16(pv0, &lV[0][(w * 64) * 8]);
    GLD16(pv1, &lV[0][(256 + w * 64) * 8]);
    pk0 += 32 * 1536; pk1 += 32 * 1536; pv0 += 32; pv1 += 32;

    int cur = 0;
    for (int t = 0; t < nt; t++) {
      const int kb0 = t * 32;
      if (t + 1 < nt) {
        const int b = cur ^ 1;
        GLD16(pk0, &lK[b][(w * 64) * 8]);
        GLD16(pk1, &lK[b][(256 + w * 64) * 8]);
        GLD16(pv0, &lV[b][(w * 64) * 8]);
        GLD16(pv1, &lV[b][(256 + w * 64) * 8]);
        pk0 += 32 * 1536; pk1 += 32 * 1536; pv0 += 32; pv1 += 32;
        __builtin_amdgcn_sched_barrier(0);
        asm volatile("s_waitcnt vmcnt(4)" ::: "memory");
      } else {
        __builtin_amdgcn_sched_barrier(0);
        asm volatile("s_waitcnt vmcnt(0)" ::: "memory");
      }
      __builtin_amdgcn_sched_barrier(0);
      __builtin_amdgcn_s_barrier();

      const unsigned short* lKc = &lK[cur][0];
      const unsigned short* lVc = &lV[cur][0];

      // S^T = K(32x128) * Q^T: thread holds keys (lg*4+r, +16) for q-row lr
      f32x4 s0 = zero4, s1 = zero4;
      __builtin_amdgcn_s_setprio(1);
#pragma unroll
      for (int kk = 0; kk < 4; kk++) {
        int c = (kk * 4 + lg) ^ (lr & 7);
        u16x8 k0f = *(const u16x8*)(lKc + lr * 128 + c * 8);
        u16x8 k1f = *(const u16x8*)(lKc + (16 + lr) * 128 + c * 8);
        s0 = mfma16(k0f, qf[kk], s0);
        s1 = mfma16(k1f, qf[kk], s1);
      }
      __builtin_amdgcn_s_setprio(0);

      float p0[4], p1[4];
      if (kb0 + 32 <= klen) {            // interior tile
#pragma unroll
        for (int r = 0; r < 4; r++) { p0[r] = s0[r]; p1[r] = s1[r]; }
      } else {                            // boundary tile: mask by key index
#pragma unroll
        for (int r = 0; r < 4; r++) {
          p0[r] = (kb0 + lg * 4 + r < klen) ? s0[r] : -1e30f;
          p1[r] = (kb0 + 16 + lg * 4 + r < klen) ? s1[r] : -1e30f;
        }
      }
      float pm = fmaxf(fmaxf(fmaxf(p0[0], p0[1]), fmaxf(p0[2], p0[3])),
                       fmaxf(fmaxf(p1[0], p1[1]), fmaxf(p1[2], p1[3])));
      pm = fmaxf(pm, __shfl_xor(pm, 16, 64));
      pm = fmaxf(pm, __shfl_xor(pm, 32, 64));

      // T13 defer-max
      if (__any(pm > mloc + 8.f)) {
        float mn = fmaxf(mloc, pm);
        float alpha = __expf(mloc - mn);
        mloc = mn;
        lseloc *= alpha;
        float aq[4];
#pragma unroll
        for (int r = 0; r < 4; r++) aq[r] = __shfl(alpha, lg * 4 + r, 64);
#pragma unroll
        for (int nb = 0; nb < 8; nb++)
#pragma unroll
          for (int r = 0; r < 4; r++) oacc[nb][r] *= aq[r];
      }
      float rs = 0.f;
#pragma unroll
      for (int r = 0; r < 4; r++) {
        p0[r] = __expf(p0[r] - mloc);
        p1[r] = __expf(p1[r] - mloc);
        rs += p0[r] + p1[r];
      }
      rs += __shfl_xor(rs, 16, 64);
      rs += __shfl_xor(rs, 32, 64);
      lseloc += rs;

      // P^T (per-thread: keys lg*4.., q=lr) -> per-wave LDS [q][key]
      ushort4 sa, sb;
      sa.x = f2bf(p0[0]); sa.y = f2bf(p0[1]); sa.z = f2bf(p0[2]); sa.w = f2bf(p0[3]);
      sb.x = f2bf(p1[0]); sb.y = f2bf(p1[1]); sb.z = f2bf(p1[2]); sb.w = f2bf(p1[3]);
      *(ushort4*)(&lP[w][lr * 40 + lg * 4]) = sa;
      *(ushort4*)(&lP[w][lr * 40 + 16 + lg * 4]) = sb;
      u16x8 pa = *(const u16x8*)(&lP[w][lr * 40 + lg * 8]);

      __builtin_amdgcn_s_setprio(1);
#pragma unroll
      for (int nb = 0; nb < 8; nb++) {
        u16x8 vf = *(const u16x8*)(lVc + (nb * 16 + lr) * 32 + lg * 8);
        oacc[nb] = mfma16(pa, vf, oacc[nb]);
      }
      __builtin_amdgcn_s_setprio(0);

      __builtin_amdgcn_s_barrier();
      cur ^= 1;
    }

    // normalize: stats live at q=lr; oacc rows are q=lg*4+r
    float invl = 1.f / lseloc;
    float inv[4];
#pragma unroll
    for (int r = 0; r < 4; r++) inv[r] = __shfl(invl, lg * 4 + r, 64);
#pragma unroll
    for (int nb = 0; nb < 8; nb++)
#pragma unroll
      for (int r = 0; r < 4; r++) osum[nb][r] += oacc[nb][r] * inv[r];
  }

#pragma unroll
  for (int nb = 0; nb < 8; nb++)
#pragma unroll
    for (int r = 0; r < 4; r++)
      out[(long)(q0 + w * 16 + lg * 4 + r) * 1536 + h * 128 + nb * 16 + lr] =
          f2bf(osum[nb][r]);
}

// ---------- launcher ----------
extern "C" void kernel_launch(void* const* d_in, const int* in_sizes, int n_in,
                              void* d_out, int out_size, void* d_ws, size_t ws_size,
                              hipStream_t stream) {
  (void)in_sizes; (void)n_in; (void)out_size; (void)ws_size;
  const float* x    = (const float*)d_in[0];
  const float* ctx  = (const float*)d_in[1];
  const float* aud  = (const float*)d_in[2];
  const float* Wq   = (const float*)d_in[3];
  const float* bq   = (const float*)d_in[4];
  const float* Wk   = (const float*)d_in[5];
  const float* bk   = (const float*)d_in[6];
  const float* Wv   = (const float*)d_in[7];
  const float* bv   = (const float*)d_in[8];
  const float* Wki  = (const float*)d_in[9];
  const float* bki  = (const float*)d_in[10];
  const float* Wvi  = (const float*)d_in[11];
  const float* bvi  = (const float*)d_in[12];
  const float* Wo   = (const float*)d_in[13];
  const float* bo   = (const float*)d_in[14];
  const float* nqw  = (const float*)d_in[15];
  const float* nkw  = (const float*)d_in[16];
  const float* nkiw = (const float*)d_in[17];
  const float* Wkp  = (const float*)d_in[18];
  const float* Wvp  = (const float*)d_in[19];
  const int* clen   = (const int*)d_in[20];
  const int* alens  = (const int*)d_in[21];
  float* out = (float*)d_out;

  char* ws = (char*)d_ws;
  size_t o = 0;
  auto alloc = [&](size_t bytes) { char* p = ws + o; o += bytes; return p; };
  unsigned short* x_bf    = (unsigned short*)alloc(33030144);  // 10752x1536
  unsigned short* ctx_bf  = (unsigned short*)alloc(2362368);   // 769x1536
  unsigned short* aud_bf  = (unsigned short*)alloc(1032192);   // 672x768
  unsigned short* Wq_bf   = (unsigned short*)alloc(4718592);
  unsigned short* Wo_bf   = (unsigned short*)alloc(4718592);
  unsigned short* Wkv_bf  = (unsigned short*)alloc(9437184);   // [Wk;Wv] 3072x1536
  unsigned short* Wkvi_bf = (unsigned short*)alloc(9437184);   // [Wki;Wvi]
  unsigned short* Wkva_bf = (unsigned short*)alloc(4718592);   // [Wkp;Wvp] 3072x768
  float* q_f32   = (float*)alloc(66060288);                    // 10752x1536 f32
  float* kvt_f32 = (float*)alloc(3145728);                     // 512x1536 (K half)
  float* kvi_f32 = (float*)alloc(1579008);                     // 257x1536 (K half)
  unsigned short* q_bf  = (unsigned short*)alloc(33030144);
  unsigned short* kt_bf = (unsigned short*)alloc(1572864);     // 512x1536
  unsigned short* ki_bf = (unsigned short*)alloc(884736);      // 288x1536 (padded)
  unsigned short* ka_bf = (unsigned short*)alloc(2064384);     // 672x1536
  unsigned short* vtT   = (unsigned short*)alloc(1572864);     // [12][128][512]
  unsigned short* viT   = (unsigned short*)alloc(884736);      // [12][128][288] (pad)
  unsigned short* vaT   = (unsigned short*)alloc(2064384);     // [21][12][128][32]
  unsigned short* attn_bf = x_bf;   // x_bf dead after Q GEMM

  // one batched convert launch for all 11 tensors
  CJobs cj;
  cj.s[0] = x;    cj.d[0] = x_bf;                       cj.n4[0] = 10752 * 1536 / 4;
  cj.s[1] = ctx;  cj.d[1] = ctx_bf;                     cj.n4[1] = 769 * 1536 / 4;
  cj.s[2] = aud;  cj.d[2] = aud_bf;                     cj.n4[2] = 672 * 768 / 4;
  cj.s[3] = Wq;   cj.d[3] = Wq_bf;                      cj.n4[3] = 1536 * 1536 / 4;
  cj.s[4] = Wo;   cj.d[4] = Wo_bf;                      cj.n4[4] = 1536 * 1536 / 4;
  cj.s[5] = Wk;   cj.d[5] = Wkv_bf;                     cj.n4[5] = 1536 * 1536 / 4;
  cj.s[6] = Wv;   cj.d[6] = Wkv_bf + 1536 * 1536;       cj.n4[6] = 1536 * 1536 / 4;
  cj.s[7] = Wki;  cj.d[7] = Wkvi_bf;                    cj.n4[7] = 1536 * 1536 / 4;
  cj.s[8] = Wvi;  cj.d[8] = Wkvi_bf + 1536 * 1536;      cj.n4[8] = 1536 * 1536 / 4;
  cj.s[9] = Wkp;  cj.d[9] = Wkva_bf;                    cj.n4[9] = 1536 * 768 / 4;
  cj.s[10] = Wvp; cj.d[10] = Wkva_bf + 1536 * 768;      cj.n4[10] = 1536 * 768 / 4;
  k_convN<<<dim3(1024, 11), 256, 0, stream>>>(cj);

  // big projection: 256^2 counted-vmcnt pipeline
  k_gemm256<<<dim3(6, 42), 512, 0, stream>>>(x_bf, Wq_bf, q_f32, 10752, 1536, 1536, bq);

  // merged small projections (KV GEMMs scatter V^T + audio-K directly as bf16)
  GJobs gj;
  gj.j[0] = { ctx_bf + 257 * 1536, Wkv_bf, kvt_f32, nullptr, vtT, 512, 512, 1536, 24, 0, bk, bv };
  gj.j[1] = { ctx_bf, Wkvi_bf, kvi_f32, nullptr, viT, 288, 257, 1536, 24, 96, bki, bvi };
  gj.j[2] = { aud_bf, Wkva_bf, nullptr, ka_bf, vaT, 32, 672, 768, 24, 168, nullptr, nullptr };
  k_gemm_small<<<312, 256, 0, stream>>>(gj);

  // merged RMSNorm + bf16 (Q gets 1/sqrt(128) folded in)
  PJobs pj;
  pj.j[0] = { q_f32, nqw, q_bf, 0.08838834764831845f, 0 };
  pj.j[1] = { kvt_f32, nkw, kt_bf, 1.0f, 10752 };
  pj.j[2] = { kvi_f32, nkiw, ki_bf, 1.0f, 11264 };
  k_postproc<<<11521, 256, 0, stream>>>(pj);

  // fused img+txt+audio attention -> bf16
  k_attn<<<dim3(168, 12), 256, 0, stream>>>(q_bf, kt_bf, vtT, ki_bf, viT, ka_bf, vaT,
                                            clen, alens, attn_bf);

  // output projection
  k_gemm256<<<dim3(6, 42), 512, 0, stream>>>(attn_bf, Wo_bf, out, 10752, 1536, 1536, bo);
}

// Round 8
// 473.544 us; speedup vs baseline: 1.6532x; 1.0407x over previous
//
#include <hip/hip_runtime.h>

// ---------- types ----------
typedef __bf16 bf16x8 __attribute__((ext_vector_type(8)));
typedef unsigned short u16x8 __attribute__((ext_vector_type(8)));
typedef float f32x4 __attribute__((ext_vector_type(4)));

__device__ __forceinline__ unsigned short f2bf(float f) {
  __bf16 b = (__bf16)f;                     // native RNE cvt
  return __builtin_bit_cast(unsigned short, b);
}
__device__ __forceinline__ float bf2f(unsigned short u) {
  unsigned v = ((unsigned)u) << 16;
  return __builtin_bit_cast(float, v);
}
__device__ __forceinline__ float fexp2(float x) {   // 2^x via v_exp_f32
  float r;
  asm("v_exp_f32 %0, %1" : "=v"(r) : "v"(x));
  return r;
}

__device__ __forceinline__ f32x4 mfma16(u16x8 a, u16x8 b, f32x4 c) {
  return __builtin_amdgcn_mfma_f32_16x16x32_bf16(
      __builtin_bit_cast(bf16x8, a), __builtin_bit_cast(bf16x8, b), c, 0, 0, 0);
}

// async global->LDS, 16B per lane; LDS dest is wave-uniform base + lane*16
#define GLD16(gp, lp)                                                              \
  __builtin_amdgcn_global_load_lds((const __attribute__((address_space(1))) void*)(gp), \
                                   (__attribute__((address_space(3))) void*)(lp), 16, 0, 0)

// ---------- batched f32 -> bf16 convert ----------
struct CJobs {
  const float* s[11];
  unsigned short* d[11];
  int n4[11];
};
__global__ __launch_bounds__(256) void k_convN(CJobs j) {
  const int job = blockIdx.y;
  const int n4 = j.n4[job];
  const float* __restrict__ src = j.s[job];
  unsigned short* __restrict__ dst = j.d[job];
  for (int i = blockIdx.x * 256 + threadIdx.x; i < n4; i += gridDim.x * 256) {
    float4 v = ((const float4*)src)[i];
    ushort4 o;
    o.x = f2bf(v.x); o.y = f2bf(v.y); o.z = f2bf(v.z); o.w = f2bf(v.w);
    ((ushort4*)dst)[i] = o;
  }
}

// ---------- big GEMM: C[M,1536] = A[M,K]bf16 * B[1536,K]^T bf16 + bias ----------
// 256x256 tile, BK=64, 8 waves, 128 KiB dbuf LDS, counted vmcnt(8).
// XCD-chunked bijective block remap (T1): each XCD gets contiguous m-major chunk.
__global__ __launch_bounds__(512, 2) void k_gemm256(const unsigned short* __restrict__ A,
                                                    const unsigned short* __restrict__ B,
                                                    float* __restrict__ Cf,
                                                    unsigned short* __restrict__ Cbf,
                                                    int M, int N, int K,
                                                    const float* __restrict__ bias) {
  __shared__ unsigned short lA[2][256 * 64];
  __shared__ unsigned short lB[2][256 * 64];
  const int tid = threadIdx.x;
  const int l = tid & 63, w = tid >> 6;
  const int wm = w >> 2, wn = w & 3;           // 2 x 4 waves
  const int lr = l & 15, lg = l >> 4;

  // bijective XCD-chunked remap (m204): hw bid b -> logical chunk_start(xcd)+b/8
  const int nwg = gridDim.x;
  const int xcd = blockIdx.x & 7, idx = blockIdx.x >> 3;
  const int q = nwg >> 3, r = nwg & 7;
  const int start = xcd < r ? xcd * (q + 1) : r * (q + 1) + (xcd - r) * q;
  const int lb = start + idx;
  const int ntx = N >> 8;
  const int m0 = (lb / ntx) * 256, n0 = (lb % ntx) * 256;

  const int srow = tid >> 3;
  const int g8 = ((tid & 7) ^ (srow & 7)) * 8;
  const unsigned short* pA = A + (long)(m0 + srow) * K + g8;
  const unsigned short* pB = B + (long)(n0 + srow) * K + g8;
  const long iStrA = (long)64 * K;

  const int rdA = (wm * 128 + lr) * 64;
  const int rdB = (wn * 64 + lr) * 64;
  const int ck[2] = { (lg ^ (lr & 7)) * 8, ((4 + lg) ^ (lr & 7)) * 8 };

  const f32x4 zero4 = {0.f, 0.f, 0.f, 0.f};
  f32x4 acc[8][4];
#pragma unroll
  for (int i = 0; i < 8; i++)
#pragma unroll
    for (int j = 0; j < 4; j++) acc[i][j] = zero4;

  const int NT = K >> 6;

#pragma unroll
  for (int i = 0; i < 4; i++) GLD16(pA + i * iStrA, &lA[0][(i * 512 + w * 64) * 8]);
#pragma unroll
  for (int i = 0; i < 4; i++) GLD16(pB + i * iStrA, &lB[0][(i * 512 + w * 64) * 8]);
  pA += 64; pB += 64;

  int cur = 0;
  for (int t = 0; t < NT; t++) {
    if (t + 1 < NT) {
      const int b = cur ^ 1;
#pragma unroll
      for (int i = 0; i < 4; i++) GLD16(pA + i * iStrA, &lA[b][(i * 512 + w * 64) * 8]);
#pragma unroll
      for (int i = 0; i < 4; i++) GLD16(pB + i * iStrA, &lB[b][(i * 512 + w * 64) * 8]);
      pA += 64; pB += 64;
      __builtin_amdgcn_sched_barrier(0);
      asm volatile("s_waitcnt vmcnt(8)" ::: "memory");
    } else {
      __builtin_amdgcn_sched_barrier(0);
      asm volatile("s_waitcnt vmcnt(0)" ::: "memory");
    }
    __builtin_amdgcn_sched_barrier(0);
    __builtin_amdgcn_s_barrier();

    const unsigned short* lAc = lA[cur];
    const unsigned short* lBc = lB[cur];
#pragma unroll
    for (int ks = 0; ks < 2; ks++) {
      u16x8 a8[8], b4[4];
#pragma unroll
      for (int mb = 0; mb < 8; mb++)
        a8[mb] = *(const u16x8*)(lAc + rdA + mb * 16 * 64 + ck[ks]);
#pragma unroll
      for (int nb = 0; nb < 4; nb++)
        b4[nb] = *(const u16x8*)(lBc + rdB + nb * 16 * 64 + ck[ks]);
#pragma unroll
      for (int mb = 0; mb < 8; mb++)
#pragma unroll
        for (int nb = 0; nb < 4; nb++) acc[mb][nb] = mfma16(a8[mb], b4[nb], acc[mb][nb]);
    }
    __builtin_amdgcn_sched_barrier(0);
    __builtin_amdgcn_s_barrier();
    cur ^= 1;
  }

#pragma unroll
  for (int mb = 0; mb < 8; mb++)
#pragma unroll
    for (int nb = 0; nb < 4; nb++) {
      const int col = n0 + wn * 64 + nb * 16 + lr;
      const float bv = bias[col];
#pragma unroll
      for (int r2 = 0; r2 < 4; r2++) {
        const int row = m0 + wm * 128 + mb * 16 + lg * 4 + r2;
        const float val = acc[mb][nb][r2] + bv;
        if (Cbf) Cbf[(long)row * N + col] = f2bf(val);
        else     Cf[(long)row * N + col] = val;
      }
    }
}

// ---------- merged small GEMMs: 3 jobs in one launch ----------
struct GJob {
  const unsigned short* A; const unsigned short* B;
  float* Cf; unsigned short* CKbf; unsigned short* CVT;
  int NK, M, K, nbx, bstart;
  const float* bias0; const float* bias1;
};
struct GJobs { GJob j[3]; };

__global__ __launch_bounds__(256) void k_gemm_small(GJobs js) {
  const int bid = blockIdx.x;
  const int ji = (bid >= js.j[1].bstart) + (bid >= js.j[2].bstart);
  const GJob J = js.j[ji];
  const int rel = bid - J.bstart;
  const int m0 = (rel / J.nbx) * 128, n0 = (rel % J.nbx) * 128;
  const int M = J.M, K = J.K;

  __shared__ unsigned short lA[128 * 32];
  __shared__ unsigned short lB[128 * 32];
  const int tid = threadIdx.x;
  const int l = tid & 63, w = tid >> 6;
  const int wm = w >> 1, wn = w & 1;
  const int lr = l & 15, lg = l >> 4;

  const int srow = w * 16 + (l >> 2);
  const int sk8 = (l & 3) * 8;
  int raA0 = m0 + srow;       if (raA0 >= M) raA0 = M - 1;
  int raA1 = m0 + 64 + srow;  if (raA1 >= M) raA1 = M - 1;
  const long rbB0 = (long)(n0 + srow) * K;
  const long rbB1 = (long)(n0 + 64 + srow) * K;
  const long raA0o = (long)raA0 * K, raA1o = (long)raA1 * K;
  unsigned short* ldsA0 = &lA[(w * 16) * 32];
  unsigned short* ldsA1 = &lA[(64 + w * 16) * 32];
  unsigned short* ldsB0 = &lB[(w * 16) * 32];
  unsigned short* ldsB1 = &lB[(64 + w * 16) * 32];

  const f32x4 zero4 = {0.f, 0.f, 0.f, 0.f};
  f32x4 acc[4][4];
#pragma unroll
  for (int i = 0; i < 4; i++)
#pragma unroll
    for (int j = 0; j < 4; j++) acc[i][j] = zero4;

  for (int k0 = 0; k0 < K; k0 += 32) {
    __syncthreads();
    GLD16(J.A + raA0o + k0 + sk8, ldsA0);
    GLD16(J.A + raA1o + k0 + sk8, ldsA1);
    GLD16(J.B + rbB0 + k0 + sk8, ldsB0);
    GLD16(J.B + rbB1 + k0 + sk8, ldsB1);
    __syncthreads();

    u16x8 af[4], bfr[4];
#pragma unroll
    for (int mb = 0; mb < 4; mb++)
      af[mb] = *(const u16x8*)(&lA[(wm * 64 + mb * 16 + lr) * 32 + lg * 8]);
#pragma unroll
    for (int nb = 0; nb < 4; nb++)
      bfr[nb] = *(const u16x8*)(&lB[(wn * 64 + nb * 16 + lr) * 32 + lg * 8]);
#pragma unroll
    for (int mb = 0; mb < 4; mb++)
#pragma unroll
      for (int nb = 0; nb < 4; nb++) acc[mb][nb] = mfma16(af[mb], bfr[nb], acc[mb][nb]);
  }

#pragma unroll
  for (int mb = 0; mb < 4; mb++)
#pragma unroll
    for (int nb = 0; nb < 4; nb++)
#pragma unroll
      for (int r = 0; r < 4; r++) {
        int row = m0 + wm * 64 + mb * 16 + lg * 4 + r;
        if (row < M) {
          int col = n0 + wn * 64 + nb * 16 + lr;
          float b = 0.f;
          if (col < 1536) { if (J.bias0) b = J.bias0[col]; }
          else            { if (J.bias1) b = J.bias1[col - 1536]; }
          float val = acc[mb][nb][r] + b;
          if (col < 1536) {
            if (J.CKbf) J.CKbf[(long)row * 1536 + col] = f2bf(val);
            else        J.Cf[(long)row * 1536 + col] = val;
          } else {
            int c2 = col - 1536, hh = c2 >> 7, dd = c2 & 127;
            long addr = (J.NK == 32)
                ? ((((long)(row >> 5) * 12 + hh) * 128 + dd) * 32 + (row & 31))
                : (((long)hh * 128 + dd) * J.NK + row);
            J.CVT[addr] = f2bf(val);
          }
        }
      }
}

// ---------- Q RMSNorm: bf16 in -> bf16 out, 192 threads/row, scale folded ----------
__global__ __launch_bounds__(192) void k_qnorm(const unsigned short* __restrict__ src,
                                               const float* __restrict__ w,
                                               unsigned short* __restrict__ dst) {
  const int row = blockIdx.x;
  u16x8 v = *(const u16x8*)(src + (long)row * 1536 + threadIdx.x * 8);
  float f[8];
  float ss = 0.f;
#pragma unroll
  for (int j = 0; j < 8; j++) { f[j] = bf2f(v[j]); ss += f[j] * f[j]; }
#pragma unroll
  for (int o = 1; o < 64; o <<= 1) ss += __shfl_xor(ss, o, 64);
  __shared__ float red[3];
  if ((threadIdx.x & 63) == 0) red[threadIdx.x >> 6] = ss;
  __syncthreads();
  float tot = red[0] + red[1] + red[2];
  // 1/sqrt(128) * log2(e) folded (attn uses exp2)
  float scale = rsqrtf(tot * (1.f / 1536.f) + 1e-6f) * 0.1275174271f;
  const float* wp = w + threadIdx.x * 8;
  u16x8 o8;
#pragma unroll
  for (int j = 0; j < 8; j++) o8[j] = f2bf(f[j] * scale * wp[j]);
  *(u16x8*)(dst + (long)row * 1536 + threadIdx.x * 8) = o8;
}

// ---------- merged per-row RMSNorm (2 jobs, f32 in) ----------
struct PJob { const float* src; const float* w; unsigned short* dst; int rstart; };
struct PJobs { PJob j[2]; };
__global__ __launch_bounds__(256) void k_postproc(PJobs js) {
  const int bid = blockIdx.x;
  const int ji = (bid >= js.j[1].rstart);
  const PJob J = js.j[ji];
  const int row = bid - J.rstart;
  const float* s = J.src + (long)row * 1536;
  float v[6];
  float ss = 0.f;
#pragma unroll
  for (int i = 0; i < 6; i++) {
    v[i] = s[threadIdx.x + i * 256];
    ss += v[i] * v[i];
  }
#pragma unroll
  for (int o = 1; o < 64; o <<= 1) ss += __shfl_xor(ss, o, 64);
  __shared__ float red[4];
  if ((threadIdx.x & 63) == 0) red[threadIdx.x >> 6] = ss;
  __syncthreads();
  float tot = red[0] + red[1] + red[2] + red[3];
  float scale = rsqrtf(tot * (1.f / 1536.f) + 1e-6f);
  unsigned short* d = J.dst + (long)row * 1536;
#pragma unroll
  for (int i = 0; i < 6; i++)
    d[threadIdx.x + i * 256] = f2bf(v[i] * scale * J.w[threadIdx.x + i * 256]);
}

// ---------- fused 3-way flash attention, KVBLK=64 ----------
// grid (168 q-tiles of 64, 12 heads), 4 waves x 16 q-rows.
// Swapped QK^T (in-lane softmax), exp2 domain (Q pre-scaled by log2e/sqrt(128)),
// XOR-swizzled K and V LDS tiles, dbuf global_load_lds staging, counted vmcnt(8).
__global__ __launch_bounds__(256) void k_attn(
    const unsigned short* __restrict__ qb, const unsigned short* __restrict__ kt,
    const unsigned short* __restrict__ vtT, const unsigned short* __restrict__ ki,
    const unsigned short* __restrict__ viT, const unsigned short* __restrict__ ka,
    const unsigned short* __restrict__ vaT, const int* __restrict__ clen_p,
    const int* __restrict__ alens, unsigned short* __restrict__ out) {
  __shared__ unsigned short lK[2][64 * 128];   // 16KB per buffer, [key][d] swizzled
  __shared__ unsigned short lV[2][128 * 64];   // 16KB per buffer, [d][key] swizzled
  __shared__ unsigned short lP[4][16 * 72];    // per-wave P (16q x 64k, stride 72)

  const int qt = blockIdx.x, h = blockIdx.y;
  const int tid = threadIdx.x, l = tid & 63, w = tid >> 6;
  const int lr = l & 15, lg = l >> 4;
  const int q0 = qt * 64;
  const int frame = qt >> 3;

  // staging lane constants (rule 21: linear LDS dest + inverse-swizzled source)
  const int kkey = tid >> 4;                          // 0..15 (+16 per issue)
  const int kchunk = ((tid & 15) ^ (kkey & 7)) * 8;   // K: 16 chunks/row
  const int vd = tid >> 3;                            // 0..31 (+32 per issue)
  const int vchunk = ((tid & 7) ^ (vd & 7)) * 8;      // V: 8 chunks/row

  u16x8 qf[4];
  {
    const unsigned short* qp = qb + (long)(q0 + w * 16 + lr) * 1536 + h * 128;
#pragma unroll
    for (int kk = 0; kk < 4; kk++) qf[kk] = *(const u16x8*)(qp + kk * 32 + lg * 8);
  }

  const f32x4 zero4 = {0.f, 0.f, 0.f, 0.f};
  f32x4 osum[8];
#pragma unroll
  for (int nb = 0; nb < 8; nb++) osum[nb] = zero4;

  for (int ph = 0; ph < 3; ph++) {
    const unsigned short *kp, *vtp;
    int klen;
    long vis;   // V issue stride = 32*NK
    if (ph == 0) {
      kp = ki; vtp = viT + (long)h * 128 * 320; klen = 257; vis = 32 * 320;
    } else if (ph == 1) {
      kp = kt; vtp = vtT + (long)h * 128 * 512; klen = clen_p[0]; vis = 32 * 512;
    } else {
      kp = ka + (long)frame * 32 * 1536;
      vtp = vaT + (long)frame * 49152 + h * 4096;
      klen = alens[frame]; vis = 32 * 32;
    }
    const long vNK = vis >> 5;

    const unsigned short* pk = kp + (long)kkey * 1536 + h * 128 + kchunk;
    const unsigned short* pv = vtp + (long)vd * vNK + vchunk;

    float mloc = -1e30f, lseloc = 0.f;
    f32x4 oacc[8];
#pragma unroll
    for (int nb = 0; nb < 8; nb++) oacc[nb] = zero4;

    const int nt = (klen + 63) >> 6;

    // stage tile 0 -> buf 0 (8 loads/thread)
#pragma unroll
    for (int i = 0; i < 4; i++) GLD16(pk + i * 24576, &lK[0][(i * 256 + w * 64) * 8]);
#pragma unroll
    for (int i = 0; i < 4; i++) GLD16(pv + i * vis, &lV[0][(i * 256 + w * 64) * 8]);
    pk += 64 * 1536; pv += 64;

    int cur = 0;
    for (int t = 0; t < nt; t++) {
      const int kb0 = t * 64;
      if (t + 1 < nt) {
        const int b = cur ^ 1;
#pragma unroll
        for (int i = 0; i < 4; i++) GLD16(pk + i * 24576, &lK[b][(i * 256 + w * 64) * 8]);
#pragma unroll
        for (int i = 0; i < 4; i++) GLD16(pv + i * vis, &lV[b][(i * 256 + w * 64) * 8]);
        pk += 64 * 1536; pv += 64;
        __builtin_amdgcn_sched_barrier(0);
        asm volatile("s_waitcnt vmcnt(8)" ::: "memory");
      } else {
        __builtin_amdgcn_sched_barrier(0);
        asm volatile("s_waitcnt vmcnt(0)" ::: "memory");
      }
      __builtin_amdgcn_sched_barrier(0);
      __builtin_amdgcn_s_barrier();

      const unsigned short* lKc = &lK[cur][0];
      const unsigned short* lVc = &lV[cur][0];

      // S^T = K(64x128) * Q^T: 4 key-blocks; thread holds key kb*16+lg*4+r, q=lr
      f32x4 s[4];
#pragma unroll
      for (int kb = 0; kb < 4; kb++) s[kb] = zero4;
      __builtin_amdgcn_s_setprio(1);
#pragma unroll
      for (int kk = 0; kk < 4; kk++) {
        const int c = ((kk * 4 + lg) ^ (lr & 7)) * 8;
#pragma unroll
        for (int kb = 0; kb < 4; kb++) {
          u16x8 kf = *(const u16x8*)(lKc + (kb * 16 + lr) * 128 + c);
          s[kb] = mfma16(kf, qf[kk], s[kb]);
        }
      }
      __builtin_amdgcn_s_setprio(0);

      float p[4][4];
      if (kb0 + 64 <= klen) {
#pragma unroll
        for (int kb = 0; kb < 4; kb++)
#pragma unroll
          for (int r = 0; r < 4; r++) p[kb][r] = s[kb][r];
      } else {
#pragma unroll
        for (int kb = 0; kb < 4; kb++)
#pragma unroll
          for (int r = 0; r < 4; r++)
            p[kb][r] = (kb0 + kb * 16 + lg * 4 + r < klen) ? s[kb][r] : -1e30f;
      }
      float pm = -1e30f;
#pragma unroll
      for (int kb = 0; kb < 4; kb++)
#pragma unroll
        for (int r = 0; r < 4; r++) pm = fmaxf(pm, p[kb][r]);
      pm = fmaxf(pm, __shfl_xor(pm, 16, 64));
      pm = fmaxf(pm, __shfl_xor(pm, 32, 64));

      // T13 defer-max (log2 domain, threshold 8 -> P <= 256)
      if (__any(pm > mloc + 8.f)) {
        float mn = fmaxf(mloc, pm);
        float alpha = fexp2(mloc - mn);
        mloc = mn;
        lseloc *= alpha;
        float aq[4];
#pragma unroll
        for (int r = 0; r < 4; r++) aq[r] = __shfl(alpha, lg * 4 + r, 64);
#pragma unroll
        for (int nb = 0; nb < 8; nb++)
#pragma unroll
          for (int r = 0; r < 4; r++) oacc[nb][r] *= aq[r];
      }
      float rs = 0.f;
#pragma unroll
      for (int kb = 0; kb < 4; kb++)
#pragma unroll
        for (int r = 0; r < 4; r++) {
          p[kb][r] = fexp2(p[kb][r] - mloc);
          rs += p[kb][r];
        }
      rs += __shfl_xor(rs, 16, 64);
      rs += __shfl_xor(rs, 32, 64);
      lseloc += rs;

      // P -> per-wave LDS [q=lr][key], 4x ushort4 stores
#pragma unroll
      for (int kb = 0; kb < 4; kb++) {
        ushort4 s4;
        s4.x = f2bf(p[kb][0]); s4.y = f2bf(p[kb][1]);
        s4.z = f2bf(p[kb][2]); s4.w = f2bf(p[kb][3]);
        *(ushort4*)(&lP[w][lr * 72 + kb * 16 + lg * 4]) = s4;
      }
      u16x8 pa0 = *(const u16x8*)(&lP[w][lr * 72 + lg * 8]);
      u16x8 pa1 = *(const u16x8*)(&lP[w][lr * 72 + 32 + lg * 8]);

      __builtin_amdgcn_s_setprio(1);
#pragma unroll
      for (int nb = 0; nb < 8; nb++) {
        const int row = (nb * 16 + lr) * 64;
        u16x8 vf0 = *(const u16x8*)(lVc + row + ((lg ^ (lr & 7)) * 8));
        u16x8 vf1 = *(const u16x8*)(lVc + row + (((4 + lg) ^ (lr & 7)) * 8));
        oacc[nb] = mfma16(pa0, vf0, oacc[nb]);
        oacc[nb] = mfma16(pa1, vf1, oacc[nb]);
      }
      __builtin_amdgcn_s_setprio(0);

      __builtin_amdgcn_s_barrier();
      cur ^= 1;
    }

    float invl = 1.f / lseloc;
    float inv[4];
#pragma unroll
    for (int r = 0; r < 4; r++) inv[r] = __shfl(invl, lg * 4 + r, 64);
#pragma unroll
    for (int nb = 0; nb < 8; nb++)
#pragma unroll
      for (int r = 0; r < 4; r++) osum[nb][r] += oacc[nb][r] * inv[r];
  }

#pragma unroll
  for (int nb = 0; nb < 8; nb++)
#pragma unroll
    for (int r = 0; r < 4; r++)
      out[(long)(q0 + w * 16 + lg * 4 + r) * 1536 + h * 128 + nb * 16 + lr] =
          f2bf(osum[nb][r]);
}

// ---------- launcher ----------
extern "C" void kernel_launch(void* const* d_in, const int* in_sizes, int n_in,
                              void* d_out, int out_size, void* d_ws, size_t ws_size,
                              hipStream_t stream) {
  (void)in_sizes; (void)n_in; (void)out_size; (void)ws_size;
  const float* x    = (const float*)d_in[0];
  const float* ctx  = (const float*)d_in[1];
  const float* aud  = (const float*)d_in[2];
  const float* Wq   = (const float*)d_in[3];
  const float* bq   = (const float*)d_in[4];
  const float* Wk   = (const float*)d_in[5];
  const float* bk   = (const float*)d_in[6];
  const float* Wv   = (const float*)d_in[7];
  const float* bv   = (const float*)d_in[8];
  const float* Wki  = (const float*)d_in[9];
  const float* bki  = (const float*)d_in[10];
  const float* Wvi  = (const float*)d_in[11];
  const float* bvi  = (const float*)d_in[12];
  const float* Wo   = (const float*)d_in[13];
  const float* bo   = (const float*)d_in[14];
  const float* nqw  = (const float*)d_in[15];
  const float* nkw  = (const float*)d_in[16];
  const float* nkiw = (const float*)d_in[17];
  const float* Wkp  = (const float*)d_in[18];
  const float* Wvp  = (const float*)d_in[19];
  const int* clen   = (const int*)d_in[20];
  const int* alens  = (const int*)d_in[21];
  float* out = (float*)d_out;

  char* ws = (char*)d_ws;
  size_t o = 0;
  auto alloc = [&](size_t bytes) { char* p = ws + o; o += bytes; return p; };
  unsigned short* x_bf    = (unsigned short*)alloc(33030144);  // 10752x1536
  unsigned short* ctx_bf  = (unsigned short*)alloc(2362368);
  unsigned short* aud_bf  = (unsigned short*)alloc(1032192);
  unsigned short* Wq_bf   = (unsigned short*)alloc(4718592);
  unsigned short* Wo_bf   = (unsigned short*)alloc(4718592);
  unsigned short* Wkv_bf  = (unsigned short*)alloc(9437184);   // [Wk;Wv]
  unsigned short* Wkvi_bf = (unsigned short*)alloc(9437184);   // [Wki;Wvi]
  unsigned short* Wkva_bf = (unsigned short*)alloc(4718592);   // [Wkp;Wvp]
  unsigned short* q_raw = (unsigned short*)alloc(33030144);    // Q GEMM out (bf16)
  float* kvt_f32 = (float*)alloc(3145728);                     // 512x1536 (K half)
  float* kvi_f32 = (float*)alloc(1579008);                     // 257x1536 (K half)
  unsigned short* q_bf  = (unsigned short*)alloc(33030144);
  unsigned short* kt_bf = (unsigned short*)alloc(1572864);     // 512x1536
  unsigned short* ki_bf = (unsigned short*)alloc(983040);      // 320x1536 (padded)
  unsigned short* ka_bf = (unsigned short*)alloc(2162688);     // 704x1536 (padded)
  unsigned short* vtT   = (unsigned short*)alloc(1572864);     // [12][128][512]
  unsigned short* viT   = (unsigned short*)alloc(983040);      // [12][128][320] (pad)
  unsigned short* vaT   = (unsigned short*)alloc(2064384);     // [21][12][128][32]
  alloc(262144);                                               // overrun slack
  unsigned short* attn_bf = x_bf;   // x_bf dead after Q GEMM

  CJobs cj;
  cj.s[0] = x;    cj.d[0] = x_bf;                       cj.n4[0] = 10752 * 1536 / 4;
  cj.s[1] = ctx;  cj.d[1] = ctx_bf;                     cj.n4[1] = 769 * 1536 / 4;
  cj.s[2] = aud;  cj.d[2] = aud_bf;                     cj.n4[2] = 672 * 768 / 4;
  cj.s[3] = Wq;   cj.d[3] = Wq_bf;                      cj.n4[3] = 1536 * 1536 / 4;
  cj.s[4] = Wo;   cj.d[4] = Wo_bf;                      cj.n4[4] = 1536 * 1536 / 4;
  cj.s[5] = Wk;   cj.d[5] = Wkv_bf;                     cj.n4[5] = 1536 * 1536 / 4;
  cj.s[6] = Wv;   cj.d[6] = Wkv_bf + 1536 * 1536;       cj.n4[6] = 1536 * 1536 / 4;
  cj.s[7] = Wki;  cj.d[7] = Wkvi_bf;                    cj.n4[7] = 1536 * 1536 / 4;
  cj.s[8] = Wvi;  cj.d[8] = Wkvi_bf + 1536 * 1536;      cj.n4[8] = 1536 * 1536 / 4;
  cj.s[9] = Wkp;  cj.d[9] = Wkva_bf;                    cj.n4[9] = 1536 * 768 / 4;
  cj.s[10] = Wvp; cj.d[10] = Wkva_bf + 1536 * 768;      cj.n4[10] = 1536 * 768 / 4;
  k_convN<<<dim3(1024, 11), 256, 0, stream>>>(cj);

  // big projection: writes bf16 directly (RMSNorm re-reads bf16)
  k_gemm256<<<252, 512, 0, stream>>>(x_bf, Wq_bf, nullptr, q_raw, 10752, 1536, 1536, bq);

  // merged small projections (V^T scatter; img NK padded to 320)
  GJobs gj;
  gj.j[0] = { ctx_bf + 257 * 1536, Wkv_bf, kvt_f32, nullptr, vtT, 512, 512, 1536, 24, 0, bk, bv };
  gj.j[1] = { ctx_bf, Wkvi_bf, kvi_f32, nullptr, viT, 320, 257, 1536, 24, 96, bki, bvi };
  gj.j[2] = { aud_bf, Wkva_bf, nullptr, ka_bf, vaT, 32, 672, 768, 24, 168, nullptr, nullptr };
  k_gemm_small<<<312, 256, 0, stream>>>(gj);

  // Q RMSNorm (bf16 in/out, log2e/sqrt(128) folded)
  k_qnorm<<<10752, 192, 0, stream>>>(q_raw, nqw, q_bf);

  // K RMSNorms (f32 in)
  PJobs pj;
  pj.j[0] = { kvt_f32, nkw, kt_bf, 0 };
  pj.j[1] = { kvi_f32, nkiw, ki_bf, 512 };
  k_postproc<<<769, 256, 0, stream>>>(pj);

  // fused img+txt+audio attention -> bf16
  k_attn<<<dim3(168, 12), 256, 0, stream>>>(q_bf, kt_bf, vtT, ki_bf, viT, ka_bf, vaT,
                                            clen, alens, attn_bf);

  // output projection (f32 to d_out)
  k_gemm256<<<252, 512, 0, stream>>>(attn_bf, Wo_bf, out, nullptr, 10752, 1536, 1536, bo);
}